// Round 3
// baseline (972.826 us; speedup 1.0000x reference)
//
#include <hip/hip_runtime.h>
#include <hip/hip_fp16.h>

// ---------------------------------------------------------------------------
// TimmPnPNystromAttention  (B=32, N=1025, C=768, H=12, Dh=64, landmarks=64)
// Round 6: pinv/expb are LDS-issue-bound at 6 waves/CU (grid=384 is
// latency-starved; 25 sequential stages can't split). Fix per-wave LDS
// efficiency with bit-identical math:
//  - mm65: k-blocked by 4, float4 reads of BOTH operands, unconditional
//    broadcast reads for row/col 64 (non-owner lanes compute valid values
//    that are never written back). ~2.7x fewer LDS cycles per stage.
//  - expb: same 5x5 float4-k-blocked register tiling (was untiled: 32 b128
//    per output element).
//
// d_out (100.8 MB): [ Xh fp16 (50.4) | Qh fp16 (50.4) ]  -> final fp32 out
//   Xh region after gemm<0>: T1part(26MB) | Mpart | @27MB KMh | @33MB T2TH
// ws (137.8 MB): Kh | Vh (fp16, CTXh aliases Kh) | fp32 smalls | WT fp16
// ---------------------------------------------------------------------------

constexpr int kN  = 1025;
constexpr int kNT = 32 * kN;      // 32800 tokens
constexpr int kBH = 32 * 12;      // 384
constexpr int NSPLIT = 4;         // n-dim split for sct1

constexpr size_t QSZ  = (size_t)kBH * kN * 64;   // 25190400 == out_size
constexpr size_t QMSZ = (size_t)kBH * 65 * 64;   // 1597440
constexpr size_t SBSZ = (size_t)kBH * 65 * 65;   // 1622400

typedef _Float16 f16x8 __attribute__((ext_vector_type(8)));
typedef float    f32x4 __attribute__((ext_vector_type(4)));

#define GLDS(gp, lp) __builtin_amdgcn_global_load_lds( \
    (const __attribute__((address_space(1))) void*)(gp), \
    (__attribute__((address_space(3))) void*)(lp), 16, 0, 0)

__device__ __forceinline__ float4 loadh4(const __half* p) {
    const __half2* q = (const __half2*)p;
    float2 a = __half22float2(q[0]);
    float2 b = __half22float2(q[1]);
    return make_float4(a.x, a.y, b.x, b.y);
}

// ---------------- K0a: fp32 -> fp16 elementwise (X) -------------------------
__global__ __launch_bounds__(256) void cvt_f32_f16(
    const float* __restrict__ src, __half* __restrict__ dst, int n4)
{
    int i = blockIdx.x * 256 + threadIdx.x;
    if (i < n4) {
        float4 v = ((const float4*)src)[i];
        __half2 h01 = __floats2half2_rn(v.x, v.y);
        __half2 h23 = __floats2half2_rn(v.z, v.w);
        ((__half2*)dst)[2 * i]     = h01;
        ((__half2*)dst)[2 * i + 1] = h23;
    }
}

// ---------------- K0b: W (rows x cols, fp32) -> WT (cols x rows, fp16) ------
__global__ __launch_bounds__(256) void cvt_transpose(
    const float* __restrict__ W, __half* __restrict__ WT, int rows, int cols)
{
    __shared__ float tile[32][33];
    const int n0 = blockIdx.x * 32, k0 = blockIdx.y * 32;
#pragma unroll
    for (int i = 0; i < 4; ++i)
        tile[threadIdx.y + i * 8][threadIdx.x] =
            W[(size_t)(k0 + threadIdx.y + i * 8) * cols + n0 + threadIdx.x];
    __syncthreads();
#pragma unroll
    for (int i = 0; i < 4; ++i)
        WT[(size_t)(n0 + threadIdx.y + i * 8) * rows + k0 + threadIdx.x] =
            __float2half_rn(tile[threadIdx.x][threadIdx.y + i * 8]);
}

// ---------------- K1/K9: fp16 MFMA GEMM, 128x128 tile, BK=64 ----------------
template<int MODE>
__global__ __launch_bounds__(256) void gemm_mfma(
    const __half* __restrict__ A, const __half* __restrict__ Bt,
    const float* __restrict__ bias,
    float* __restrict__ OutF, __half* __restrict__ Qo,
    __half* __restrict__ Ko, __half* __restrict__ Vo)
{
    __shared__ _Float16 As[128 * 64];
    __shared__ _Float16 Bs[128 * 64];
    const int t  = threadIdx.x;
    const int w  = t >> 6, L = t & 63;
    const int q  = L >> 4, ln = L & 15;
    const int wm = w >> 1, wn = w & 1;
    const int cb = blockIdx.x * 128, rb = blockIdx.y * 128;

    f32x4 acc[4][4];
#pragma unroll
    for (int i = 0; i < 4; ++i)
#pragma unroll
        for (int j = 0; j < 4; ++j) acc[i][j] = (f32x4)0.f;

    const int srow = L >> 3;
    const int sc   = L & 7;

    for (int kt = 0; kt < 12; ++kt) {
        const int k0 = kt * 64;
        __syncthreads();
#pragma unroll
        for (int i = 0; i < 4; ++i) {
            const int r0  = w * 32 + i * 8;
            const int row = r0 + srow;
            const int g   = sc ^ (row & 7);
            if (rb + row < kNT)
                GLDS(A + (size_t)(rb + row) * 768 + k0 + g * 8, &As[r0 * 64]);
            GLDS(Bt + (size_t)(cb + row) * 768 + k0 + g * 8, &Bs[r0 * 64]);
        }
        __syncthreads();
#pragma unroll
        for (int kc = 0; kc < 2; ++kc) {
            f16x8 af[4], bf[4];
#pragma unroll
            for (int im = 0; im < 4; ++im) {
                const int m    = wm * 64 + im * 16 + ln;
                const int slot = (kc * 4 + q) ^ (m & 7);
                af[im] = *(const f16x8*)&As[m * 64 + slot * 8];
            }
#pragma unroll
            for (int in = 0; in < 4; ++in) {
                const int n    = wn * 64 + in * 16 + ln;
                const int slot = (kc * 4 + q) ^ (n & 7);
                bf[in] = *(const f16x8*)&Bs[n * 64 + slot * 8];
            }
#pragma unroll
            for (int im = 0; im < 4; ++im)
#pragma unroll
                for (int in = 0; in < 4; ++in)
                    acc[im][in] = __builtin_amdgcn_mfma_f32_16x16x32_f16(
                        af[im], bf[in], acc[im][in], 0, 0, 0);
        }
    }

    float bcol[4];
#pragma unroll
    for (int in = 0; in < 4; ++in) bcol[in] = bias[cb + wn * 64 + in * 16 + ln];

    if (MODE == 0) {
#pragma unroll
        for (int in = 0; in < 4; ++in) {
            const int Ncol  = cb + wn * 64 + in * 16 + ln;
            const int which = Ncol / 768;
            const int cm    = Ncol - which * 768;
            const int h     = cm >> 6, d0 = cm & 63;
            __half* dst = (which == 0) ? Qo : (which == 1) ? Ko : Vo;
            const float scl = (which == 0) ? 0.125f : 1.f;
#pragma unroll
            for (int im = 0; im < 4; ++im) {
                const int Rb2 = rb + wm * 64 + im * 16 + q * 4;
#pragma unroll
                for (int reg = 0; reg < 4; ++reg) {
                    const int R = Rb2 + reg;
                    if (R < kNT) {
                        const int bidx = R / 1025, nn = R - bidx * 1025;
                        dst[((size_t)(bidx * 12 + h) * 1025 + nn) * 64 + d0] =
                            __float2half_rn((acc[im][in][reg] + bcol[in]) * scl);
                    }
                }
            }
        }
    } else {
#pragma unroll
        for (int im = 0; im < 4; ++im) {
            const int Rb2 = rb + wm * 64 + im * 16 + q * 4;
#pragma unroll
            for (int reg = 0; reg < 4; ++reg) {
                const int R = Rb2 + reg;
                if (R < kNT) {
#pragma unroll
                    for (int in = 0; in < 4; ++in) {
                        const int Ncol = cb + wn * 64 + in * 16 + ln;
                        OutF[(size_t)R * 768 + Ncol] = acc[im][in][reg] + bcol[in];
                    }
                }
            }
        }
    }
}

// ---------------- K2: landmark pooling (fp16 src -> fp32 + fp16 Km) ---------
__global__ __launch_bounds__(64) void pool_kernel(
    const __half* __restrict__ Qh, const __half* __restrict__ Kh,
    float* __restrict__ QM, float* __restrict__ KM, __half* __restrict__ KMh)
{
    const int d  = threadIdx.x;
    const int m  = blockIdx.x;
    const int bh = blockIdx.y;
    if (m >= 65) {
        if (blockIdx.z == 1)
            KMh[(size_t)bh * 6144 + m * 64 + d] = __float2half_rn(0.f);
        return;
    }
    const __half* sb = (blockIdx.z ? Kh : Qh) + (size_t)bh * kN * 64;
    float* dst = blockIdx.z ? KM : QM;
    float v;
    if (m == 0) {
        v = __half2float(sb[d]);
    } else {
        int l = m - 1, a = l >> 3, e = l & 7;
        const __half* base = sb + (size_t)(1 + a * 128 + e * 4) * 64 + d;
        float s = 0.f;
#pragma unroll
        for (int b4 = 0; b4 < 4; ++b4)
#pragma unroll
            for (int f = 0; f < 4; ++f)
                s += __half2float(base[(b4 * 32 + f) * 64]);
        v = s * 0.0625f;
    }
    dst[(size_t)bh * 65 * 64 + m * 64 + d] = v;
    if (blockIdx.z == 1)
        KMh[(size_t)bh * 6144 + m * 64 + d] = __float2half_rn(v);
}

// ---------------- K3+K7 fused: partial online-softmax T1 --------------------
__global__ __launch_bounds__(256) void sct1_kernel(
    const float* __restrict__ QM, const __half* __restrict__ Kg,
    const __half* __restrict__ Vg, float* __restrict__ T1part,
    float* __restrict__ Mpart)
{
    __shared__ float QmT[64][68];
    __shared__ float Wt[64][68];
    __shared__ float ET[64][68];
    const int t  = threadIdx.x;
    const int sp = blockIdx.x, bh = blockIdx.y;
    const float* qm = QM + (size_t)bh * 4160;
    const __half* Kb = Kg + (size_t)bh * 65600;
    const __half* Vb = Vg + (size_t)bh * 65600;

    for (int s = 0; s < 5; ++s) {
        int idx = t + s * 256;
        if (idx < 1040) {
            int r = idx >> 4, c = idx & 15;
            float4 v = *(const float4*)(qm + r * 64 + c * 4);
            QmT[c * 4 + 0][r] = v.x; QmT[c * 4 + 1][r] = v.y;
            QmT[c * 4 + 2][r] = v.z; QmT[c * 4 + 3][r] = v.w;
        }
    }
    const int tm = t >> 4, tn = t & 15;
    float acc2[5][5];
    float run_m[5];
#pragma unroll
    for (int i = 0; i < 5; ++i) {
        run_m[i] = -1e30f;
#pragma unroll
        for (int j = 0; j < 5; ++j) acc2[i][j] = 0.f;
    }

    const int tstart = (sp == 0) ? 0 : 1 + 4 * sp;
    const int tcount = (sp == 0) ? 5 : 4;

    for (int tt = 0; tt < tcount; ++tt) {
        const int n0 = (tstart + tt) * 64;
        __syncthreads();
        for (int s = 0; s < 4; ++s) {
            int idx = t + s * 256;
            int r = idx >> 4, c = idx & 15;
            int n = n0 + r;
            float4 v = make_float4(0.f, 0.f, 0.f, 0.f);
            if (n < kN) v = loadh4(Kb + (size_t)n * 64 + c * 4);
            Wt[c * 4 + 0][r] = v.x; Wt[c * 4 + 1][r] = v.y;
            Wt[c * 4 + 2][r] = v.z; Wt[c * 4 + 3][r] = v.w;
        }
        __syncthreads();
        float acc[5][4];
#pragma unroll
        for (int i = 0; i < 5; ++i)
#pragma unroll
            for (int j = 0; j < 4; ++j) acc[i][j] = 0.f;
        for (int k = 0; k < 64; ++k) {
            float a[5], b[4];
            float4 av = *(const float4*)&QmT[k][tm * 4];
            a[0] = av.x; a[1] = av.y; a[2] = av.z; a[3] = av.w;
            a[4] = (tm == 0) ? QmT[k][64] : 0.f;
            float4 bv = *(const float4*)&Wt[k][tn * 4];
            b[0] = bv.x; b[1] = bv.y; b[2] = bv.z; b[3] = bv.w;
#pragma unroll
            for (int i = 0; i < 5; ++i)
#pragma unroll
                for (int j = 0; j < 4; ++j)
                    acc[i][j] = fmaf(a[i], b[j], acc[i][j]);
        }
        float tmax[5];
#pragma unroll
        for (int i = 0; i < 5; ++i) tmax[i] = -3e38f;
#pragma unroll
        for (int j = 0; j < 4; ++j) {
            if (n0 + tn * 4 + j < kN) {
#pragma unroll
                for (int i = 0; i < 4; ++i) tmax[i] = fmaxf(tmax[i], acc[i][j]);
                if (tm == 0) tmax[4] = fmaxf(tmax[4], acc[4][j]);
            }
        }
#pragma unroll
        for (int mk = 1; mk < 16; mk <<= 1)
#pragma unroll
            for (int i = 0; i < 5; ++i)
                tmax[i] = fmaxf(tmax[i], __shfl_xor(tmax[i], mk));
        float nm[5];
#pragma unroll
        for (int i = 0; i < 5; ++i) {
            nm[i] = fmaxf(run_m[i], tmax[i]);
            float f = __expf(run_m[i] - nm[i]);
            run_m[i] = nm[i];
#pragma unroll
            for (int j = 0; j < 5; ++j) acc2[i][j] *= f;
        }
#pragma unroll
        for (int j = 0; j < 4; ++j) {
            int nn = tn * 4 + j;
            bool valid = (n0 + nn) < kN;
#pragma unroll
            for (int i = 0; i < 4; ++i)
                ET[nn][tm * 4 + i] = valid ? __expf(acc[i][j] - nm[i]) : 0.f;
            if (tm == 0)
                ET[nn][64] = valid ? __expf(acc[4][j] - nm[4]) : 0.f;
        }
        __syncthreads();
        for (int s = 0; s < 4; ++s) {
            int idx = t + s * 256;
            int r = idx >> 4, c = idx & 15;
            int n = n0 + r;
            float4 v = make_float4(0.f, 0.f, 0.f, 0.f);
            if (n < kN) v = loadh4(Vb + (size_t)n * 64 + c * 4);
            *(float4*)&Wt[r][c * 4] = v;
        }
        if (t < 64) Wt[t][64] = 1.f;
        __syncthreads();
        for (int nn = 0; nn < 64; ++nn) {
            float a[5], b[5];
            float4 av = *(const float4*)&ET[nn][tm * 4];
            a[0] = av.x; a[1] = av.y; a[2] = av.z; a[3] = av.w;
            a[4] = (tm == 0) ? ET[nn][64] : 0.f;
            float4 bv = *(const float4*)&Wt[nn][tn * 4];
            b[0] = bv.x; b[1] = bv.y; b[2] = bv.z; b[3] = bv.w;
            b[4] = (tn == 0) ? Wt[nn][64] : 0.f;
#pragma unroll
            for (int i = 0; i < 5; ++i)
#pragma unroll
                for (int j = 0; j < 5; ++j)
                    acc2[i][j] = fmaf(a[i], b[j], acc2[i][j]);
        }
    }
    float* T1b = T1part + ((size_t)bh * NSPLIT + sp) * 4225;
#pragma unroll
    for (int i = 0; i < 5; ++i) {
        if (i == 4 && tm != 0) continue;
        int m = (i < 4) ? tm * 4 + i : 64;
#pragma unroll
        for (int j = 0; j < 5; ++j) {
            if (j == 4 && tn != 0) continue;
            int jc = (j < 4) ? tn * 4 + j : 64;
            T1b[m * 65 + jc] = acc2[i][j];
        }
    }
    if (tn == 0) {
        float* Mb = Mpart + ((size_t)bh * NSPLIT + sp) * 65;
#pragma unroll
        for (int i = 0; i < 4; ++i) Mb[tm * 4 + i] = run_m[i];
        if (tm == 0) Mb[64] = run_m[4];
    }
}

// ---------------- combine: T1 = sum_s exp(m_s - M) * T1part_s ; emit MAXC ---
__global__ __launch_bounds__(256) void t1comb_kernel(
    const float* __restrict__ T1part, const float* __restrict__ Mpart,
    float* __restrict__ T1, float* __restrict__ MAXC)
{
    __shared__ float w[NSPLIT][65];
    const int t = threadIdx.x, bh = blockIdx.x;
    const float* Mb = Mpart + (size_t)bh * NSPLIT * 65;
    if (t < 65) {
        float m0 = Mb[t], m1 = Mb[65 + t], m2 = Mb[130 + t], m3 = Mb[195 + t];
        float M = fmaxf(fmaxf(m0, m1), fmaxf(m2, m3));
        MAXC[(size_t)bh * 65 + t] = M;
        w[0][t] = __expf(m0 - M); w[1][t] = __expf(m1 - M);
        w[2][t] = __expf(m2 - M); w[3][t] = __expf(m3 - M);
    }
    __syncthreads();
    const float* Tb = T1part + (size_t)bh * NSPLIT * 4225;
    float* To = T1 + (size_t)bh * 4225;
    for (int s = 0; s < 17; ++s) {
        int o = t + s * 256;
        if (o < 4225) {
            int m = o / 65;
            To[o] = w[0][m] * Tb[o] + w[1][m] * Tb[4225 + o]
                  + w[2][m] * Tb[8450 + o] + w[3][m] * Tb[12675 + o];
        }
    }
}

// ---------------- K4: expB = exp(max(qm@km^T - maxC, -88)); row/col sums ----
// 5x5 register tile per thread, k-blocked float4 reads (bit-identical math).
__global__ __launch_bounds__(256) void expb_kernel(
    const float* __restrict__ QM, const float* __restrict__ KM,
    const float* __restrict__ MAXC, float* __restrict__ EXPB,
    float* __restrict__ RC)
{
    __shared__ float Qs[65][68];
    __shared__ float Ks[65][68];
    __shared__ float SB[65][68];
    __shared__ float mc[65];
    __shared__ float rs[65], cs[65];
    const int t = threadIdx.x, bh = blockIdx.x;
    const float* qm = QM + (size_t)bh * 4160;
    const float* km = KM + (size_t)bh * 4160;
    for (int s = 0; s < 5; ++s) {
        int idx = t + s * 256;
        if (idx < 1040) {
            int r = idx >> 4, c = (idx & 15) * 4;
            *(float4*)&Qs[r][c] = *(const float4*)(qm + r * 64 + c);
            *(float4*)&Ks[r][c] = *(const float4*)(km + r * 64 + c);
        }
    }
    if (t < 65) mc[t] = MAXC[(size_t)bh * 65 + t];
    __syncthreads();

    const int tm = t >> 4, tj = t & 15;
    float acc[5][5];
#pragma unroll
    for (int i = 0; i < 5; ++i)
#pragma unroll
        for (int j = 0; j < 5; ++j) acc[i][j] = 0.f;
#pragma unroll 2
    for (int k4 = 0; k4 < 64; k4 += 4) {
        float Qa[5][4], Kb[5][4];
#pragma unroll
        for (int i = 0; i < 5; ++i) {
            float4 v4 = (i < 4) ? *(const float4*)&Qs[tm * 4 + i][k4]
                                : *(const float4*)&Qs[64][k4];
            Qa[i][0] = v4.x; Qa[i][1] = v4.y; Qa[i][2] = v4.z; Qa[i][3] = v4.w;
        }
#pragma unroll
        for (int j = 0; j < 5; ++j) {
            float4 v4 = (j < 4) ? *(const float4*)&Ks[tj * 4 + j][k4]
                                : *(const float4*)&Ks[64][k4];
            Kb[j][0] = v4.x; Kb[j][1] = v4.y; Kb[j][2] = v4.z; Kb[j][3] = v4.w;
        }
#pragma unroll
        for (int kk = 0; kk < 4; ++kk)
#pragma unroll
            for (int i = 0; i < 5; ++i)
#pragma unroll
                for (int j = 0; j < 5; ++j)
                    acc[i][j] = fmaf(Qa[i][kk], Kb[j][kk], acc[i][j]);
    }
#pragma unroll
    for (int i = 0; i < 5; ++i) {
        if (i == 4 && tm != 0) continue;
        const int mi = (i < 4) ? tm * 4 + i : 64;
        const float mci = mc[mi];
#pragma unroll
        for (int j = 0; j < 5; ++j) {
            if (j == 4 && tj != 0) continue;
            const int jc = (j < 4) ? tj * 4 + j : 64;
            SB[mi][jc] = __expf(fmaxf(acc[i][j] - mci, -88.f));
        }
    }
    __syncthreads();
    for (int s = 0; s < 17; ++s) {
        int o = t + s * 256;
        if (o < 4225) EXPB[(size_t)bh * 4225 + o] = SB[o / 65][o % 65];
    }
    if (t < 65) {
        float r = 0.f, c = 0.f;
        for (int j = 0; j < 65; ++j) r += SB[t][j];
        for (int i = 0; i < 65; ++i) c += SB[i][t];
        rs[t] = r; cs[t] = c;
    }
    __syncthreads();
    if (t == 0) {
        float rm = 0.f, cm2 = 0.f;
        for (int i = 0; i < 65; ++i) { rm = fmaxf(rm, rs[i]); cm2 = fmaxf(cm2, cs[i]); }
        RC[bh * 2] = rm; RC[bh * 2 + 1] = cm2;
    }
}

// ---------------- K5: alpha = 1/(global_max_rowsum * global_max_colsum + eps)
__global__ __launch_bounds__(256) void alpha_kernel(
    const float* __restrict__ RC, float* __restrict__ GMX)
{
    __shared__ float sr[256], sc[256];
    const int t = threadIdx.x;
    float rm = 0.f, cm = 0.f;
    for (int i = t; i < kBH; i += 256) {
        rm = fmaxf(rm, RC[2 * i]);
        cm = fmaxf(cm, RC[2 * i + 1]);
    }
    sr[t] = rm; sc[t] = cm;
    __syncthreads();
    for (int s = 128; s > 0; s >>= 1) {
        if (t < s) { sr[t] = fmaxf(sr[t], sr[t + s]); sc[t] = fmaxf(sc[t], sc[t + s]); }
        __syncthreads();
    }
    if (t == 0) GMX[0] = 1.f / (sr[0] * sc[0] + 1e-15f);
}

// ---------------- K6: Newton-Schulz pinv (6 iters) + T2TH = (Z@T1)^T fp16 ---
// k-blocked float4 reads, broadcast row/col-64 (bit-identical accumulation).
__device__ __forceinline__ void mm65(const float (*Op1)[68], const float (*Op2)[68],
                                     float (*Dst)[68], const float (*Pre)[68],
                                     float c0, float c1, int tm, int tj)
{
    float acc[5][5];
#pragma unroll
    for (int i = 0; i < 5; ++i)
#pragma unroll
        for (int j = 0; j < 5; ++j) acc[i][j] = 0.f;
#pragma unroll 2
    for (int k4 = 0; k4 < 64; k4 += 4) {
        float Aa[5][4], Bb[4][4], c64[4];
#pragma unroll
        for (int i = 0; i < 5; ++i) {
            float4 v4 = (i < 4) ? *(const float4*)&Op1[tm * 4 + i][k4]
                                : *(const float4*)&Op1[64][k4];
            Aa[i][0] = v4.x; Aa[i][1] = v4.y; Aa[i][2] = v4.z; Aa[i][3] = v4.w;
        }
#pragma unroll
        for (int kk = 0; kk < 4; ++kk) {
            float4 v4 = *(const float4*)&Op2[k4 + kk][tj * 4];
            Bb[kk][0] = v4.x; Bb[kk][1] = v4.y; Bb[kk][2] = v4.z; Bb[kk][3] = v4.w;
            c64[kk] = Op2[k4 + kk][64];
        }
#pragma unroll
        for (int kk = 0; kk < 4; ++kk)
#pragma unroll
            for (int i = 0; i < 5; ++i) {
                const float av = Aa[i][kk];
#pragma unroll
                for (int j = 0; j < 4; ++j)
                    acc[i][j] = fmaf(av, Bb[kk][j], acc[i][j]);
                acc[i][4] = fmaf(av, c64[kk], acc[i][4]);
            }
    }
    {   // tail k = 64
        float a5[5], b5[5];
#pragma unroll
        for (int i = 0; i < 4; ++i) a5[i] = Op1[tm * 4 + i][64];
        a5[4] = Op1[64][64];
#pragma unroll
        for (int j = 0; j < 4; ++j) b5[j] = Op2[64][tj * 4 + j];
        b5[4] = Op2[64][64];
#pragma unroll
        for (int i = 0; i < 5; ++i)
#pragma unroll
            for (int j = 0; j < 5; ++j)
                acc[i][j] = fmaf(a5[i], b5[j], acc[i][j]);
    }
    float val[5][5];
#pragma unroll
    for (int i = 0; i < 5; ++i) {
        int mi = (i < 4) ? tm * 4 + i : 64;
#pragma unroll
        for (int j = 0; j < 5; ++j) {
            int jc = (j < 4) ? tj * 4 + j : 64;
            val[i][j] = c1 * (c0 * Pre[mi][jc] - acc[i][j]);
        }
    }
    __syncthreads();
#pragma unroll
    for (int i = 0; i < 5; ++i) {
        if (i == 4 && tm != 0) continue;
        int mi = (i < 4) ? tm * 4 + i : 64;
#pragma unroll
        for (int j = 0; j < 5; ++j) {
            if (j == 4 && tj != 0) continue;
            int jc = (j < 4) ? tj * 4 + j : 64;
            Dst[mi][jc] = val[i][j];
        }
    }
    __syncthreads();
}

__global__ __launch_bounds__(256) void pinv_kernel(
    const float* __restrict__ EXPB, const float* __restrict__ T1,
    const float* __restrict__ GMX, __half* __restrict__ T2TH)
{
    __shared__ float Wb[65][68];
    __shared__ float Zb[65][68];
    __shared__ float Ab[65][68];
    const int t = threadIdx.x, bh = blockIdx.x;
    const int tm = t >> 4, tj = t & 15;
    const float alpha = GMX[0];
    const float* X = EXPB + (size_t)bh * 4225;
    for (int s = 0; s < 17; ++s) {
        int o = t + s * 256;
        if (o < 4225) Wb[o / 65][o % 65] = X[o];
    }
    __syncthreads();
    for (int s = 0; s < 17; ++s) {   // Z = alpha * X^T
        int o = t + s * 256;
        if (o < 4225) { int i = o / 65, j = o % 65; Zb[i][j] = alpha * Wb[j][i]; }
    }
    __syncthreads();
    for (int it = 0; it < 6; ++it) {
        if (it > 0) {
            for (int s = 0; s < 17; ++s) {
                int o = t + s * 256;
                if (o < 4225) Wb[o / 65][o % 65] = X[o];
            }
            __syncthreads();
        }
        mm65(Wb, Zb, Ab, Wb, 0.f,  -1.f,  tm, tj);  // A = X@Z
        mm65(Ab, Ab, Wb, Ab, 7.f,   1.f,  tm, tj);  // U = 7A - A@A    -> W
        mm65(Ab, Wb, Ab, Ab, 15.f,  1.f,  tm, tj);  // V = 15A - A@U   -> A
        mm65(Zb, Ab, Zb, Zb, 13.f,  0.25f, tm, tj); // Z = .25(13Z - Z@V)
    }
    for (int s = 0; s < 17; ++s) {
        int o = t + s * 256;
        if (o < 4225) Wb[o / 65][o % 65] = T1[(size_t)bh * 4225 + o];
    }
    __syncthreads();
    {
        float acc[5][5];
#pragma unroll
        for (int i = 0; i < 5; ++i)
#pragma unroll
            for (int j = 0; j < 5; ++j) acc[i][j] = 0.f;
#pragma unroll 2
        for (int k4 = 0; k4 < 64; k4 += 4) {
            float Aa[5][4], Bb[4][4], c64[4];
#pragma unroll
            for (int i = 0; i < 5; ++i) {
                float4 v4 = (i < 4) ? *(const float4*)&Zb[tm * 4 + i][k4]
                                    : *(const float4*)&Zb[64][k4];
                Aa[i][0] = v4.x; Aa[i][1] = v4.y; Aa[i][2] = v4.z; Aa[i][3] = v4.w;
            }
#pragma unroll
            for (int kk = 0; kk < 4; ++kk) {
                float4 v4 = *(const float4*)&Wb[k4 + kk][tj * 4];
                Bb[kk][0] = v4.x; Bb[kk][1] = v4.y; Bb[kk][2] = v4.z; Bb[kk][3] = v4.w;
                c64[kk] = Wb[k4 + kk][64];
            }
#pragma unroll
            for (int kk = 0; kk < 4; ++kk)
#pragma unroll
                for (int i = 0; i < 5; ++i) {
                    const float av = Aa[i][kk];
#pragma unroll
                    for (int j = 0; j < 4; ++j)
                        acc[i][j] = fmaf(av, Bb[kk][j], acc[i][j]);
                    acc[i][4] = fmaf(av, c64[kk], acc[i][4]);
                }
        }
        {   // tail k = 64
            float a5[5], b5[5];
#pragma unroll
            for (int i = 0; i < 4; ++i) a5[i] = Zb[tm * 4 + i][64];
            a5[4] = Zb[64][64];
#pragma unroll
            for (int j = 0; j < 4; ++j) b5[j] = Wb[64][tj * 4 + j];
            b5[4] = Wb[64][64];
#pragma unroll
            for (int i = 0; i < 5; ++i)
#pragma unroll
                for (int j = 0; j < 5; ++j)
                    acc[i][j] = fmaf(a5[i], b5[j], acc[i][j]);
        }
        // stash T2 into Ab, then emit transposed zero-padded fp16 [80][96]
        __syncthreads();
#pragma unroll
        for (int i = 0; i < 5; ++i) {
            if (i == 4 && tm != 0) continue;
            int mi = (i < 4) ? tm * 4 + i : 64;
#pragma unroll
            for (int j = 0; j < 5; ++j) {
                if (j == 4 && tj != 0) continue;
                int jc = (j < 4) ? tj * 4 + j : 64;
                Ab[mi][jc] = acc[i][j];
            }
        }
    }
    __syncthreads();
    __half* dstT = T2TH + (size_t)bh * 7680;
    for (int o = t; o < 7680; o += 256) {
        int n = o / 96, k = o - n * 96;
        float v = (n < 65 && k < 65) ? Ab[k][n] : 0.f;
        dstT[o] = __float2half_rn(v);
    }
}

// ---------------- K8: MFMA prod: P=exp(Q@Km^T); ctx = (P@T2)/(P@t2den) ------
__global__ __launch_bounds__(256) void prod_mfma(
    const __half* __restrict__ Qg, const __half* __restrict__ KMh,
    const __half* __restrict__ T2TH, __half* __restrict__ CTXh)
{
    __shared__ _Float16 Ps[128 * 104];   // P tile, stride 104 (pad) halves
    __shared__ float dn[128];
    const int t = threadIdx.x;
    const int w = t >> 6, L = t & 63;
    const int q = L >> 4, ln = L & 15;
    const int nb = blockIdx.x, bh = blockIdx.y;
    const int bq = bh / 12, h = bh % 12;
    const int n0 = nb * 128;
    const __half* Qb  = Qg   + (size_t)bh * 65600;
    const __half* Kmb = KMh  + (size_t)bh * 6144;
    const __half* Tb  = T2TH + (size_t)bh * 7680;

    // phase A: S = Q(128x64) @ Km^T (96 cols; rows>=65 of Km are zero)
    f32x4 accA[2][6];
#pragma unroll
    for (int i = 0; i < 2; ++i)
#pragma unroll
        for (int j = 0; j < 6; ++j) accA[i][j] = (f32x4)0.f;

#pragma unroll
    for (int kc = 0; kc < 2; ++kc) {
        f16x8 af[2], bf[6];
#pragma unroll
        for (int im = 0; im < 2; ++im) {
            int r = n0 + w * 32 + im * 16 + ln;
            if (r > 1024) r = 1024;
            af[im] = *(const f16x8*)(Qb + (size_t)r * 64 + (kc * 4 + q) * 8);
        }
#pragma unroll
        for (int in = 0; in < 6; ++in)
            bf[in] = *(const f16x8*)(Kmb + (size_t)(in * 16 + ln) * 64 + (kc * 4 + q) * 8);
#pragma unroll
        for (int im = 0; im < 2; ++im)
#pragma unroll
            for (int in = 0; in < 6; ++in)
                accA[im][in] = __builtin_amdgcn_mfma_f32_16x16x32_f16(
                    af[im], bf[in], accA[im][in], 0, 0, 0);
    }
#pragma unroll
    for (int im = 0; im < 2; ++im) {
        const int row = w * 32 + im * 16 + q * 4;
#pragma unroll
        for (int in = 0; in < 6; ++in) {
            const int col = in * 16 + ln;
#pragma unroll
            for (int reg = 0; reg < 4; ++reg)
                Ps[(row + reg) * 104 + col] = (_Float16)__expf(accA[im][in][reg]);
        }
    }
    __syncthreads();

    // phase B: prod = P(128x96) @ T2T^T(96x80); cols 0..63 ctx, col 64 = den
    f32x4 accB[2][5];
#pragma unroll
    for (int i = 0; i < 2; ++i)
#pragma unroll
        for (int j = 0; j < 5; ++j) accB[i][j] = (f32x4)0.f;
#pragma unroll
    for (int kc = 0; kc < 3; ++kc) {
        f16x8 pa[2], tb[5];
#pragma unroll
        for (int im = 0; im < 2; ++im)
            pa[im] = *(const f16x8*)&Ps[(w * 32 + im * 16 + ln) * 104 + (kc * 4 + q) * 8];
#pragma unroll
        for (int in = 0; in < 5; ++in)
            tb[in] = *(const f16x8*)(Tb + (size_t)(in * 16 + ln) * 96 + (kc * 4 + q) * 8);
#pragma unroll
        for (int im = 0; im < 2; ++im)
#pragma unroll
            for (int in = 0; in < 5; ++in)
                accB[im][in] = __builtin_amdgcn_mfma_f32_16x16x32_f16(
                    pa[im], tb[in], accB[im][in], 0, 0, 0);
    }
    if (ln == 0) {
#pragma unroll
        for (int im = 0; im < 2; ++im) {
            const int row = w * 32 + im * 16 + q * 4;
#pragma unroll
            for (int reg = 0; reg < 4; ++reg)
                dn[row + reg] = accB[im][4][reg];
        }
    }
    __syncthreads();
#pragma unroll
    for (int im = 0; im < 2; ++im) {
        const int rowb = w * 32 + im * 16 + q * 4;
#pragma unroll
        for (int reg = 0; reg < 4; ++reg) {
            const int n = n0 + rowb + reg;
            if (n < kN) {
                const float dv = fmaxf(dn[rowb + reg], 1e-8f);
                __half* dst = CTXh + ((size_t)bq * 1025 + n) * 768 + h * 64;
#pragma unroll
                for (int in = 0; in < 4; ++in)
                    dst[in * 16 + ln] = __float2half_rn(accB[im][in][reg] / dv);
            }
        }
    }
}

// ---------------------------------------------------------------------------
extern "C" void kernel_launch(void* const* d_in, const int* in_sizes, int n_in,
                              void* d_out, int out_size, void* d_ws, size_t ws_size,
                              hipStream_t stream)
{
    const float* x      = (const float*)d_in[0];
    const float* qkv_w  = (const float*)d_in[1];
    const float* qkv_b  = (const float*)d_in[2];
    const float* proj_w = (const float*)d_in[3];
    const float* proj_b = (const float*)d_in[4];
    float* out = (float*)d_out;

    __half* Xh = (__half*)d_out;
    __half* Qh = Xh + QSZ;
    float*  T1part = (float*)d_out;
    float*  Mpart  = T1part + (size_t)kBH * NSPLIT * 4225;
    __half* KMh  = (__half*)((char*)d_out + (size_t)27 * 1024 * 1024);
    __half* T2TH = (__half*)((char*)d_out + (size_t)33 * 1024 * 1024);

    __half* Kh   = (__half*)d_ws;
    __half* Vh   = Kh + QSZ;
    __half* CTXh = Kh;
    float*  QM   = (float*)(Vh + QSZ);
    float*  KM   = QM + QMSZ;
    float*  MAXC = KM + QMSZ;
    float*  EXPB = MAXC + (size_t)kBH * 65;
    float*  T1   = EXPB + SBSZ;
    float*  T2   = T1 + SBSZ;
    float*  RC   = T2 + SBSZ;
    float*  GMX  = RC + (size_t)kBH * 2;
    size_t woff = (size_t)(GMX + 1 - (float*)d_ws);
    woff = (woff + 3) & ~(size_t)3;
    __half* WqkvT = (__half*)((float*)d_ws + woff);
    __half* WprojT = WqkvT + (size_t)2304 * 768;

    cvt_f32_f16  <<<dim3((int)(QSZ / 4 / 256)), 256, 0, stream>>>(x, Xh, (int)(QSZ / 4));
    cvt_transpose<<<dim3(72, 24), dim3(32, 8), 0, stream>>>(qkv_w, WqkvT, 768, 2304);
    cvt_transpose<<<dim3(24, 24), dim3(32, 8), 0, stream>>>(proj_w, WprojT, 768, 768);

    gemm_mfma<0><<<dim3(18, 257), 256, 0, stream>>>(Xh, WqkvT, qkv_b,
                                                    nullptr, Qh, Kh, Vh);
    pool_kernel<<<dim3(96, kBH, 2), 64, 0, stream>>>(Qh, Kh, QM, KM, KMh);
    sct1_kernel<<<dim3(NSPLIT, kBH), 256, 0, stream>>>(QM, Kh, Vh, T1part, Mpart);
    t1comb_kernel<<<dim3(kBH), 256, 0, stream>>>(T1part, Mpart, T1, MAXC);
    expb_kernel<<<dim3(kBH), 256, 0, stream>>>(QM, KM, MAXC, EXPB, RC);
    alpha_kernel<<<dim3(1), 256, 0, stream>>>(RC, GMX);
    pinv_kernel<<<dim3(kBH), 256, 0, stream>>>(EXPB, T1, GMX, T2TH);
    prod_mfma  <<<dim3(9, kBH), 256, 0, stream>>>(Qh, KMh, T2TH, CTXh);
    gemm_mfma<1><<<dim3(6, 257), 256, 0, stream>>>(CTXh, WprojT, proj_b,
                                                   out, nullptr, nullptr, nullptr);
}

// Round 4
// 872.708 us; speedup vs baseline: 1.1147x; 1.1147x over previous
//
#include <hip/hip_runtime.h>
#include <hip/hip_fp16.h>

// ---------------------------------------------------------------------------
// TimmPnPNystromAttention  (B=32, N=1025, C=768, H=12, Dh=64, landmarks=64)
// Round 7:
//  - gemm_mfma<0> epilogue: stage fp16 C-tile in LDS (reuse As/Bs, stride 136,
//    XOR-quad swizzle) -> coalesced f16x8 stores. Replaces 48 scattered 2-B
//    stores/thread (WRITE_SIZE 270 MB vs 151 ideal) with 8 16-B stores.
//  - pinv/expb: 512 threads (2 rows x 4 cols per thread, broadcast row/col 64)
//    to double occupancy on the grid-starved 384-block kernels.
//  All bit-identical (same per-element fma chains, same convert points).
//
// d_out (100.8 MB): [ Xh fp16 (50.4) | Qh fp16 (50.4) ]  -> final fp32 out
//   Xh region after gemm<0>: T1part(26MB) | Mpart | @27MB KMh | @33MB T2TH
// ws (137.8 MB): Kh | Vh (fp16, CTXh aliases Kh) | fp32 smalls | WT fp16
// ---------------------------------------------------------------------------

constexpr int kN  = 1025;
constexpr int kNT = 32 * kN;      // 32800 tokens
constexpr int kBH = 32 * 12;      // 384
constexpr int NSPLIT = 4;         // n-dim split for sct1

constexpr size_t QSZ  = (size_t)kBH * kN * 64;   // 25190400 == out_size
constexpr size_t QMSZ = (size_t)kBH * 65 * 64;   // 1597440
constexpr size_t SBSZ = (size_t)kBH * 65 * 65;   // 1622400

typedef _Float16 f16x8 __attribute__((ext_vector_type(8)));
typedef float    f32x4 __attribute__((ext_vector_type(4)));

#define GLDS(gp, lp) __builtin_amdgcn_global_load_lds( \
    (const __attribute__((address_space(1))) void*)(gp), \
    (__attribute__((address_space(3))) void*)(lp), 16, 0, 0)

__device__ __forceinline__ float4 loadh4(const __half* p) {
    const __half2* q = (const __half2*)p;
    float2 a = __half22float2(q[0]);
    float2 b = __half22float2(q[1]);
    return make_float4(a.x, a.y, b.x, b.y);
}

// ---------------- K0a: fp32 -> fp16 elementwise (X) -------------------------
__global__ __launch_bounds__(256) void cvt_f32_f16(
    const float* __restrict__ src, __half* __restrict__ dst, int n4)
{
    int i = blockIdx.x * 256 + threadIdx.x;
    if (i < n4) {
        float4 v = ((const float4*)src)[i];
        __half2 h01 = __floats2half2_rn(v.x, v.y);
        __half2 h23 = __floats2half2_rn(v.z, v.w);
        ((__half2*)dst)[2 * i]     = h01;
        ((__half2*)dst)[2 * i + 1] = h23;
    }
}

// ---------------- K0b: W (rows x cols, fp32) -> WT (cols x rows, fp16) ------
__global__ __launch_bounds__(256) void cvt_transpose(
    const float* __restrict__ W, __half* __restrict__ WT, int rows, int cols)
{
    __shared__ float tile[32][33];
    const int n0 = blockIdx.x * 32, k0 = blockIdx.y * 32;
#pragma unroll
    for (int i = 0; i < 4; ++i)
        tile[threadIdx.y + i * 8][threadIdx.x] =
            W[(size_t)(k0 + threadIdx.y + i * 8) * cols + n0 + threadIdx.x];
    __syncthreads();
#pragma unroll
    for (int i = 0; i < 4; ++i)
        WT[(size_t)(n0 + threadIdx.y + i * 8) * rows + k0 + threadIdx.x] =
            __float2half_rn(tile[threadIdx.x][threadIdx.y + i * 8]);
}

// ---------------- K1/K9: fp16 MFMA GEMM, 128x128 tile, BK=64 ----------------
// MODE 0: LDS-staged fp16 epilogue -> coalesced Q/K/V writes (Q scaled 0.125).
// MODE 1: fp32 out+bias direct.
template<int MODE>
__global__ __launch_bounds__(256) void gemm_mfma(
    const __half* __restrict__ A, const __half* __restrict__ Bt,
    const float* __restrict__ bias,
    float* __restrict__ OutF, __half* __restrict__ Qo,
    __half* __restrict__ Ko, __half* __restrict__ Vo)
{
    __shared__ _Float16 SMEM[128 * 136];     // 34,816 B
    _Float16* As = SMEM;                     // [128][64] during K-loop
    _Float16* Bs = SMEM + 128 * 64;          // [128][64]
    const int t  = threadIdx.x;
    const int w  = t >> 6, L = t & 63;
    const int q  = L >> 4, ln = L & 15;
    const int wm = w >> 1, wn = w & 1;
    const int cb = blockIdx.x * 128, rb = blockIdx.y * 128;

    f32x4 acc[4][4];
#pragma unroll
    for (int i = 0; i < 4; ++i)
#pragma unroll
        for (int j = 0; j < 4; ++j) acc[i][j] = (f32x4)0.f;

    const int srow = L >> 3;
    const int sc   = L & 7;

    for (int kt = 0; kt < 12; ++kt) {
        const int k0 = kt * 64;
        __syncthreads();
#pragma unroll
        for (int i = 0; i < 4; ++i) {
            const int r0  = w * 32 + i * 8;
            const int row = r0 + srow;
            const int g   = sc ^ (row & 7);
            if (rb + row < kNT)
                GLDS(A + (size_t)(rb + row) * 768 + k0 + g * 8, &As[r0 * 64]);
            GLDS(Bt + (size_t)(cb + row) * 768 + k0 + g * 8, &Bs[r0 * 64]);
        }
        __syncthreads();
#pragma unroll
        for (int kc = 0; kc < 2; ++kc) {
            f16x8 af[4], bf[4];
#pragma unroll
            for (int im = 0; im < 4; ++im) {
                const int m    = wm * 64 + im * 16 + ln;
                const int slot = (kc * 4 + q) ^ (m & 7);
                af[im] = *(const f16x8*)&As[m * 64 + slot * 8];
            }
#pragma unroll
            for (int in = 0; in < 4; ++in) {
                const int n    = wn * 64 + in * 16 + ln;
                const int slot = (kc * 4 + q) ^ (n & 7);
                bf[in] = *(const f16x8*)&Bs[n * 64 + slot * 8];
            }
#pragma unroll
            for (int im = 0; im < 4; ++im)
#pragma unroll
                for (int in = 0; in < 4; ++in)
                    acc[im][in] = __builtin_amdgcn_mfma_f32_16x16x32_f16(
                        af[im], bf[in], acc[im][in], 0, 0, 0);
        }
    }

    float bcol[4];
#pragma unroll
    for (int in = 0; in < 4; ++in) bcol[in] = bias[cb + wn * 64 + in * 16 + ln];

    if (MODE == 0) {
        // which/scale/head-base are block-uniform (128-col blocks, 768 per qkv)
        const int   which = cb / 768;
        const float scl   = (which == 0) ? 0.125f : 1.f;
        __syncthreads();                     // all LDS reads of As/Bs done
        // stage fp16 C tile: row stride 136 halves (16B-aligned rows),
        // col ^ (q<<4) swizzle -> conflict-free b16 writes
#pragma unroll
        for (int in = 0; in < 4; ++in) {
            const int col = wn * 64 + in * 16 + ln;
#pragma unroll
            for (int im = 0; im < 4; ++im) {
                const int rowb = wm * 64 + im * 16 + q * 4;
#pragma unroll
                for (int reg = 0; reg < 4; ++reg)
                    SMEM[(rowb + reg) * 136 + (col ^ (q << 4))] =
                        (_Float16)((acc[im][in][reg] + bcol[in]) * scl);
            }
        }
        __syncthreads();
        const int hb = (cb - which * 768) >> 6;
        __half* dstb = (which == 0) ? Qo : (which == 1) ? Ko : Vo;
#pragma unroll
        for (int s = 0; s < 8; ++s) {
            const int idx = t + s * 256;         // 2048 chunks of 8 halves
            const int r = idx >> 4, ck = idx & 15;
            const int R = rb + r;
            if (R < kNT) {
                const int qr = (r >> 2) & 3;
                f16x8 v = *(const f16x8*)&SMEM[r * 136 + ((ck ^ (qr << 1)) << 3)];
                const int bidx = R / 1025, nn = R - bidx * 1025;
                const int h = hb + (ck >> 3), d0 = (ck & 7) * 8;
                *(f16x8*)(dstb + ((size_t)(bidx * 12 + h) * 1025 + nn) * 64 + d0) = v;
            }
        }
    } else {
#pragma unroll
        for (int im = 0; im < 4; ++im) {
            const int Rb2 = rb + wm * 64 + im * 16 + q * 4;
#pragma unroll
            for (int reg = 0; reg < 4; ++reg) {
                const int R = Rb2 + reg;
                if (R < kNT) {
#pragma unroll
                    for (int in = 0; in < 4; ++in) {
                        const int Ncol = cb + wn * 64 + in * 16 + ln;
                        OutF[(size_t)R * 768 + Ncol] = acc[im][in][reg] + bcol[in];
                    }
                }
            }
        }
    }
}

// ---------------- K2: landmark pooling (fp16 src -> fp32 + fp16 Km) ---------
__global__ __launch_bounds__(64) void pool_kernel(
    const __half* __restrict__ Qh, const __half* __restrict__ Kh,
    float* __restrict__ QM, float* __restrict__ KM, __half* __restrict__ KMh)
{
    const int d  = threadIdx.x;
    const int m  = blockIdx.x;
    const int bh = blockIdx.y;
    if (m >= 65) {
        if (blockIdx.z == 1)
            KMh[(size_t)bh * 6144 + m * 64 + d] = __float2half_rn(0.f);
        return;
    }
    const __half* sb = (blockIdx.z ? Kh : Qh) + (size_t)bh * kN * 64;
    float* dst = blockIdx.z ? KM : QM;
    float v;
    if (m == 0) {
        v = __half2float(sb[d]);
    } else {
        int l = m - 1, a = l >> 3, e = l & 7;
        const __half* base = sb + (size_t)(1 + a * 128 + e * 4) * 64 + d;
        float s = 0.f;
#pragma unroll
        for (int b4 = 0; b4 < 4; ++b4)
#pragma unroll
            for (int f = 0; f < 4; ++f)
                s += __half2float(base[(b4 * 32 + f) * 64]);
        v = s * 0.0625f;
    }
    dst[(size_t)bh * 65 * 64 + m * 64 + d] = v;
    if (blockIdx.z == 1)
        KMh[(size_t)bh * 6144 + m * 64 + d] = __float2half_rn(v);
}

// ---------------- K3+K7 fused: partial online-softmax T1 --------------------
__global__ __launch_bounds__(256) void sct1_kernel(
    const float* __restrict__ QM, const __half* __restrict__ Kg,
    const __half* __restrict__ Vg, float* __restrict__ T1part,
    float* __restrict__ Mpart)
{
    __shared__ float QmT[64][68];
    __shared__ float Wt[64][68];
    __shared__ float ET[64][68];
    const int t  = threadIdx.x;
    const int sp = blockIdx.x, bh = blockIdx.y;
    const float* qm = QM + (size_t)bh * 4160;
    const __half* Kb = Kg + (size_t)bh * 65600;
    const __half* Vb = Vg + (size_t)bh * 65600;

    for (int s = 0; s < 5; ++s) {
        int idx = t + s * 256;
        if (idx < 1040) {
            int r = idx >> 4, c = idx & 15;
            float4 v = *(const float4*)(qm + r * 64 + c * 4);
            QmT[c * 4 + 0][r] = v.x; QmT[c * 4 + 1][r] = v.y;
            QmT[c * 4 + 2][r] = v.z; QmT[c * 4 + 3][r] = v.w;
        }
    }
    const int tm = t >> 4, tn = t & 15;
    float acc2[5][5];
    float run_m[5];
#pragma unroll
    for (int i = 0; i < 5; ++i) {
        run_m[i] = -1e30f;
#pragma unroll
        for (int j = 0; j < 5; ++j) acc2[i][j] = 0.f;
    }

    const int tstart = (sp == 0) ? 0 : 1 + 4 * sp;
    const int tcount = (sp == 0) ? 5 : 4;

    for (int tt = 0; tt < tcount; ++tt) {
        const int n0 = (tstart + tt) * 64;
        __syncthreads();
        for (int s = 0; s < 4; ++s) {
            int idx = t + s * 256;
            int r = idx >> 4, c = idx & 15;
            int n = n0 + r;
            float4 v = make_float4(0.f, 0.f, 0.f, 0.f);
            if (n < kN) v = loadh4(Kb + (size_t)n * 64 + c * 4);
            Wt[c * 4 + 0][r] = v.x; Wt[c * 4 + 1][r] = v.y;
            Wt[c * 4 + 2][r] = v.z; Wt[c * 4 + 3][r] = v.w;
        }
        __syncthreads();
        float acc[5][4];
#pragma unroll
        for (int i = 0; i < 5; ++i)
#pragma unroll
            for (int j = 0; j < 4; ++j) acc[i][j] = 0.f;
        for (int k = 0; k < 64; ++k) {
            float a[5], b[4];
            float4 av = *(const float4*)&QmT[k][tm * 4];
            a[0] = av.x; a[1] = av.y; a[2] = av.z; a[3] = av.w;
            a[4] = (tm == 0) ? QmT[k][64] : 0.f;
            float4 bv = *(const float4*)&Wt[k][tn * 4];
            b[0] = bv.x; b[1] = bv.y; b[2] = bv.z; b[3] = bv.w;
#pragma unroll
            for (int i = 0; i < 5; ++i)
#pragma unroll
                for (int j = 0; j < 4; ++j)
                    acc[i][j] = fmaf(a[i], b[j], acc[i][j]);
        }
        float tmax[5];
#pragma unroll
        for (int i = 0; i < 5; ++i) tmax[i] = -3e38f;
#pragma unroll
        for (int j = 0; j < 4; ++j) {
            if (n0 + tn * 4 + j < kN) {
#pragma unroll
                for (int i = 0; i < 4; ++i) tmax[i] = fmaxf(tmax[i], acc[i][j]);
                if (tm == 0) tmax[4] = fmaxf(tmax[4], acc[4][j]);
            }
        }
#pragma unroll
        for (int mk = 1; mk < 16; mk <<= 1)
#pragma unroll
            for (int i = 0; i < 5; ++i)
                tmax[i] = fmaxf(tmax[i], __shfl_xor(tmax[i], mk));
        float nm[5];
#pragma unroll
        for (int i = 0; i < 5; ++i) {
            nm[i] = fmaxf(run_m[i], tmax[i]);
            float f = __expf(run_m[i] - nm[i]);
            run_m[i] = nm[i];
#pragma unroll
            for (int j = 0; j < 5; ++j) acc2[i][j] *= f;
        }
#pragma unroll
        for (int j = 0; j < 4; ++j) {
            int nn = tn * 4 + j;
            bool valid = (n0 + nn) < kN;
#pragma unroll
            for (int i = 0; i < 4; ++i)
                ET[nn][tm * 4 + i] = valid ? __expf(acc[i][j] - nm[i]) : 0.f;
            if (tm == 0)
                ET[nn][64] = valid ? __expf(acc[4][j] - nm[4]) : 0.f;
        }
        __syncthreads();
        for (int s = 0; s < 4; ++s) {
            int idx = t + s * 256;
            int r = idx >> 4, c = idx & 15;
            int n = n0 + r;
            float4 v = make_float4(0.f, 0.f, 0.f, 0.f);
            if (n < kN) v = loadh4(Vb + (size_t)n * 64 + c * 4);
            *(float4*)&Wt[r][c * 4] = v;
        }
        if (t < 64) Wt[t][64] = 1.f;
        __syncthreads();
        for (int nn = 0; nn < 64; ++nn) {
            float a[5], b[5];
            float4 av = *(const float4*)&ET[nn][tm * 4];
            a[0] = av.x; a[1] = av.y; a[2] = av.z; a[3] = av.w;
            a[4] = (tm == 0) ? ET[nn][64] : 0.f;
            float4 bv = *(const float4*)&Wt[nn][tn * 4];
            b[0] = bv.x; b[1] = bv.y; b[2] = bv.z; b[3] = bv.w;
            b[4] = (tn == 0) ? Wt[nn][64] : 0.f;
#pragma unroll
            for (int i = 0; i < 5; ++i)
#pragma unroll
                for (int j = 0; j < 5; ++j)
                    acc2[i][j] = fmaf(a[i], b[j], acc2[i][j]);
        }
    }
    float* T1b = T1part + ((size_t)bh * NSPLIT + sp) * 4225;
#pragma unroll
    for (int i = 0; i < 5; ++i) {
        if (i == 4 && tm != 0) continue;
        int m = (i < 4) ? tm * 4 + i : 64;
#pragma unroll
        for (int j = 0; j < 5; ++j) {
            if (j == 4 && tn != 0) continue;
            int jc = (j < 4) ? tn * 4 + j : 64;
            T1b[m * 65 + jc] = acc2[i][j];
        }
    }
    if (tn == 0) {
        float* Mb = Mpart + ((size_t)bh * NSPLIT + sp) * 65;
#pragma unroll
        for (int i = 0; i < 4; ++i) Mb[tm * 4 + i] = run_m[i];
        if (tm == 0) Mb[64] = run_m[4];
    }
}

// ---------------- combine: T1 = sum_s exp(m_s - M) * T1part_s ; emit MAXC ---
__global__ __launch_bounds__(256) void t1comb_kernel(
    const float* __restrict__ T1part, const float* __restrict__ Mpart,
    float* __restrict__ T1, float* __restrict__ MAXC)
{
    __shared__ float w[NSPLIT][65];
    const int t = threadIdx.x, bh = blockIdx.x;
    const float* Mb = Mpart + (size_t)bh * NSPLIT * 65;
    if (t < 65) {
        float m0 = Mb[t], m1 = Mb[65 + t], m2 = Mb[130 + t], m3 = Mb[195 + t];
        float M = fmaxf(fmaxf(m0, m1), fmaxf(m2, m3));
        MAXC[(size_t)bh * 65 + t] = M;
        w[0][t] = __expf(m0 - M); w[1][t] = __expf(m1 - M);
        w[2][t] = __expf(m2 - M); w[3][t] = __expf(m3 - M);
    }
    __syncthreads();
    const float* Tb = T1part + (size_t)bh * NSPLIT * 4225;
    float* To = T1 + (size_t)bh * 4225;
    for (int s = 0; s < 17; ++s) {
        int o = t + s * 256;
        if (o < 4225) {
            int m = o / 65;
            To[o] = w[0][m] * Tb[o] + w[1][m] * Tb[4225 + o]
                  + w[2][m] * Tb[8450 + o] + w[3][m] * Tb[12675 + o];
        }
    }
}

// ---------------- K4: expB (512 threads, 2x4 tile + broadcast row/col 64) ---
__global__ __launch_bounds__(512) void expb_kernel(
    const float* __restrict__ QM, const float* __restrict__ KM,
    const float* __restrict__ MAXC, float* __restrict__ EXPB,
    float* __restrict__ RC)
{
    __shared__ float Qs[65][68];
    __shared__ float Ks[65][68];
    __shared__ float SB[65][68];
    __shared__ float mc[65];
    __shared__ float rs[65], cs[65];
    const int t = threadIdx.x, bh = blockIdx.x;
    const float* qm = QM + (size_t)bh * 4160;
    const float* km = KM + (size_t)bh * 4160;
    for (int s = 0; s < 3; ++s) {
        int idx = t + s * 512;
        if (idx < 1040) {
            int r = idx >> 4, c = (idx & 15) * 4;
            *(float4*)&Qs[r][c] = *(const float4*)(qm + r * 64 + c);
            *(float4*)&Ks[r][c] = *(const float4*)(km + r * 64 + c);
        }
    }
    if (t < 65) mc[t] = MAXC[(size_t)bh * 65 + t];
    __syncthreads();

    const int tm = t >> 4, tj = t & 15;   // rows {2tm,2tm+1,[64]}, cols {tj*4..,[64]}
    float acc[3][5];
#pragma unroll
    for (int i = 0; i < 3; ++i)
#pragma unroll
        for (int j = 0; j < 5; ++j) acc[i][j] = 0.f;
#pragma unroll 2
    for (int k4 = 0; k4 < 64; k4 += 4) {
        float Qa[3][4], Kb[5][4];
#pragma unroll
        for (int i = 0; i < 3; ++i) {
            float4 v4 = (i < 2) ? *(const float4*)&Qs[2 * tm + i][k4]
                                : *(const float4*)&Qs[64][k4];
            Qa[i][0] = v4.x; Qa[i][1] = v4.y; Qa[i][2] = v4.z; Qa[i][3] = v4.w;
        }
#pragma unroll
        for (int j = 0; j < 5; ++j) {
            float4 v4 = (j < 4) ? *(const float4*)&Ks[tj * 4 + j][k4]
                                : *(const float4*)&Ks[64][k4];
            Kb[j][0] = v4.x; Kb[j][1] = v4.y; Kb[j][2] = v4.z; Kb[j][3] = v4.w;
        }
#pragma unroll
        for (int kk = 0; kk < 4; ++kk)
#pragma unroll
            for (int i = 0; i < 3; ++i)
#pragma unroll
                for (int j = 0; j < 5; ++j)
                    acc[i][j] = fmaf(Qa[i][kk], Kb[j][kk], acc[i][j]);
    }
#pragma unroll
    for (int i = 0; i < 3; ++i) {
        if (i == 2 && tm != 0) continue;
        const int mi = (i < 2) ? 2 * tm + i : 64;
        const float mci = mc[mi];
#pragma unroll
        for (int j = 0; j < 5; ++j) {
            if (j == 4 && tj != 0) continue;
            const int jc = (j < 4) ? tj * 4 + j : 64;
            SB[mi][jc] = __expf(fmaxf(acc[i][j] - mci, -88.f));
        }
    }
    __syncthreads();
    for (int s = 0; s < 9; ++s) {
        int o = t + s * 512;
        if (o < 4225) EXPB[(size_t)bh * 4225 + o] = SB[o / 65][o % 65];
    }
    if (t < 65) {
        float r = 0.f, c = 0.f;
        for (int j = 0; j < 65; ++j) r += SB[t][j];
        for (int i = 0; i < 65; ++i) c += SB[i][t];
        rs[t] = r; cs[t] = c;
    }
    __syncthreads();
    if (t == 0) {
        float rm = 0.f, cm2 = 0.f;
        for (int i = 0; i < 65; ++i) { rm = fmaxf(rm, rs[i]); cm2 = fmaxf(cm2, cs[i]); }
        RC[bh * 2] = rm; RC[bh * 2 + 1] = cm2;
    }
}

// ---------------- K5: alpha = 1/(global_max_rowsum * global_max_colsum + eps)
__global__ __launch_bounds__(256) void alpha_kernel(
    const float* __restrict__ RC, float* __restrict__ GMX)
{
    __shared__ float sr[256], sc[256];
    const int t = threadIdx.x;
    float rm = 0.f, cm = 0.f;
    for (int i = t; i < kBH; i += 256) {
        rm = fmaxf(rm, RC[2 * i]);
        cm = fmaxf(cm, RC[2 * i + 1]);
    }
    sr[t] = rm; sc[t] = cm;
    __syncthreads();
    for (int s = 128; s > 0; s >>= 1) {
        if (t < s) { sr[t] = fmaxf(sr[t], sr[t + s]); sc[t] = fmaxf(sc[t], sc[t + s]); }
        __syncthreads();
    }
    if (t == 0) GMX[0] = 1.f / (sr[0] * sc[0] + 1e-15f);
}

// ---------------- K6: Newton-Schulz pinv (512 threads, 2x4 tile) ------------
__device__ __forceinline__ void mm65(const float (*Op1)[68], const float (*Op2)[68],
                                     float (*Dst)[68], const float (*Pre)[68],
                                     float c0, float c1, int tm, int tj)
{
    float acc[3][5];
#pragma unroll
    for (int i = 0; i < 3; ++i)
#pragma unroll
        for (int j = 0; j < 5; ++j) acc[i][j] = 0.f;
#pragma unroll 2
    for (int k4 = 0; k4 < 64; k4 += 4) {
        float Aa[3][4], Bb[4][4], c64[4];
#pragma unroll
        for (int i = 0; i < 3; ++i) {
            float4 v4 = (i < 2) ? *(const float4*)&Op1[2 * tm + i][k4]
                                : *(const float4*)&Op1[64][k4];
            Aa[i][0] = v4.x; Aa[i][1] = v4.y; Aa[i][2] = v4.z; Aa[i][3] = v4.w;
        }
#pragma unroll
        for (int kk = 0; kk < 4; ++kk) {
            float4 v4 = *(const float4*)&Op2[k4 + kk][tj * 4];
            Bb[kk][0] = v4.x; Bb[kk][1] = v4.y; Bb[kk][2] = v4.z; Bb[kk][3] = v4.w;
            c64[kk] = Op2[k4 + kk][64];
        }
#pragma unroll
        for (int kk = 0; kk < 4; ++kk)
#pragma unroll
            for (int i = 0; i < 3; ++i) {
                const float av = Aa[i][kk];
#pragma unroll
                for (int j = 0; j < 4; ++j)
                    acc[i][j] = fmaf(av, Bb[kk][j], acc[i][j]);
                acc[i][4] = fmaf(av, c64[kk], acc[i][4]);
            }
    }
    {   // tail k = 64
        float a3[3], b5[5];
        a3[0] = Op1[2 * tm][64]; a3[1] = Op1[2 * tm + 1][64]; a3[2] = Op1[64][64];
#pragma unroll
        for (int j = 0; j < 4; ++j) b5[j] = Op2[64][tj * 4 + j];
        b5[4] = Op2[64][64];
#pragma unroll
        for (int i = 0; i < 3; ++i)
#pragma unroll
            for (int j = 0; j < 5; ++j)
                acc[i][j] = fmaf(a3[i], b5[j], acc[i][j]);
    }
    float val[3][5];
#pragma unroll
    for (int i = 0; i < 3; ++i) {
        int mi = (i < 2) ? 2 * tm + i : 64;
#pragma unroll
        for (int j = 0; j < 5; ++j) {
            int jc = (j < 4) ? tj * 4 + j : 64;
            val[i][j] = c1 * (c0 * Pre[mi][jc] - acc[i][j]);
        }
    }
    __syncthreads();
#pragma unroll
    for (int i = 0; i < 3; ++i) {
        if (i == 2 && tm != 0) continue;
        int mi = (i < 2) ? 2 * tm + i : 64;
#pragma unroll
        for (int j = 0; j < 5; ++j) {
            if (j == 4 && tj != 0) continue;
            int jc = (j < 4) ? tj * 4 + j : 64;
            Dst[mi][jc] = val[i][j];
        }
    }
    __syncthreads();
}

__global__ __launch_bounds__(512) void pinv_kernel(
    const float* __restrict__ EXPB, const float* __restrict__ T1,
    const float* __restrict__ GMX, __half* __restrict__ T2TH)
{
    __shared__ float Wb[65][68];
    __shared__ float Zb[65][68];
    __shared__ float Ab[65][68];
    const int t = threadIdx.x, bh = blockIdx.x;
    const int tm = t >> 4, tj = t & 15;
    const float alpha = GMX[0];
    const float* X = EXPB + (size_t)bh * 4225;
    for (int s = 0; s < 9; ++s) {
        int o = t + s * 512;
        if (o < 4225) Wb[o / 65][o % 65] = X[o];
    }
    __syncthreads();
    for (int s = 0; s < 9; ++s) {   // Z = alpha * X^T
        int o = t + s * 512;
        if (o < 4225) { int i = o / 65, j = o % 65; Zb[i][j] = alpha * Wb[j][i]; }
    }
    __syncthreads();
    for (int it = 0; it < 6; ++it) {
        if (it > 0) {
            for (int s = 0; s < 9; ++s) {
                int o = t + s * 512;
                if (o < 4225) Wb[o / 65][o % 65] = X[o];
            }
            __syncthreads();
        }
        mm65(Wb, Zb, Ab, Wb, 0.f,  -1.f,  tm, tj);  // A = X@Z
        mm65(Ab, Ab, Wb, Ab, 7.f,   1.f,  tm, tj);  // U = 7A - A@A    -> W
        mm65(Ab, Wb, Ab, Ab, 15.f,  1.f,  tm, tj);  // V = 15A - A@U   -> A
        mm65(Zb, Ab, Zb, Zb, 13.f,  0.25f, tm, tj); // Z = .25(13Z - Z@V)
    }
    for (int s = 0; s < 9; ++s) {
        int o = t + s * 512;
        if (o < 4225) Wb[o / 65][o % 65] = T1[(size_t)bh * 4225 + o];
    }
    __syncthreads();
    {
        float acc[3][5];
#pragma unroll
        for (int i = 0; i < 3; ++i)
#pragma unroll
            for (int j = 0; j < 5; ++j) acc[i][j] = 0.f;
#pragma unroll 2
        for (int k4 = 0; k4 < 64; k4 += 4) {
            float Aa[3][4], Bb[4][4], c64[4];
#pragma unroll
            for (int i = 0; i < 3; ++i) {
                float4 v4 = (i < 2) ? *(const float4*)&Zb[2 * tm + i][k4]
                                    : *(const float4*)&Zb[64][k4];
                Aa[i][0] = v4.x; Aa[i][1] = v4.y; Aa[i][2] = v4.z; Aa[i][3] = v4.w;
            }
#pragma unroll
            for (int kk = 0; kk < 4; ++kk) {
                float4 v4 = *(const float4*)&Wb[k4 + kk][tj * 4];
                Bb[kk][0] = v4.x; Bb[kk][1] = v4.y; Bb[kk][2] = v4.z; Bb[kk][3] = v4.w;
                c64[kk] = Wb[k4 + kk][64];
            }
#pragma unroll
            for (int kk = 0; kk < 4; ++kk)
#pragma unroll
                for (int i = 0; i < 3; ++i) {
                    const float av = Aa[i][kk];
#pragma unroll
                    for (int j = 0; j < 4; ++j)
                        acc[i][j] = fmaf(av, Bb[kk][j], acc[i][j]);
                    acc[i][4] = fmaf(av, c64[kk], acc[i][4]);
                }
        }
        {   // tail k = 64
            float a3[3], b5[5];
            a3[0] = Zb[2 * tm][64]; a3[1] = Zb[2 * tm + 1][64]; a3[2] = Zb[64][64];
#pragma unroll
            for (int j = 0; j < 4; ++j) b5[j] = Wb[64][tj * 4 + j];
            b5[4] = Wb[64][64];
#pragma unroll
            for (int i = 0; i < 3; ++i)
#pragma unroll
                for (int j = 0; j < 5; ++j)
                    acc[i][j] = fmaf(a3[i], b5[j], acc[i][j]);
        }
        __syncthreads();
#pragma unroll
        for (int i = 0; i < 3; ++i) {
            if (i == 2 && tm != 0) continue;
            int mi = (i < 2) ? 2 * tm + i : 64;
#pragma unroll
            for (int j = 0; j < 5; ++j) {
                if (j == 4 && tj != 0) continue;
                int jc = (j < 4) ? tj * 4 + j : 64;
                Ab[mi][jc] = acc[i][j];
            }
        }
    }
    __syncthreads();
    __half* dstT = T2TH + (size_t)bh * 7680;
    for (int o = t; o < 7680; o += 512) {
        int n = o / 96, k = o - n * 96;
        float v = (n < 65 && k < 65) ? Ab[k][n] : 0.f;
        dstT[o] = __float2half_rn(v);
    }
}

// ---------------- K8: MFMA prod: P=exp(Q@Km^T); ctx = (P@T2)/(P@t2den) ------
__global__ __launch_bounds__(256) void prod_mfma(
    const __half* __restrict__ Qg, const __half* __restrict__ KMh,
    const __half* __restrict__ T2TH, __half* __restrict__ CTXh)
{
    __shared__ _Float16 Ps[128 * 104];   // P tile, stride 104 (pad) halves
    __shared__ float dn[128];
    const int t = threadIdx.x;
    const int w = t >> 6, L = t & 63;
    const int q = L >> 4, ln = L & 15;
    const int nb = blockIdx.x, bh = blockIdx.y;
    const int bq = bh / 12, h = bh % 12;
    const int n0 = nb * 128;
    const __half* Qb  = Qg   + (size_t)bh * 65600;
    const __half* Kmb = KMh  + (size_t)bh * 6144;
    const __half* Tb  = T2TH + (size_t)bh * 7680;

    // phase A: S = Q(128x64) @ Km^T (96 cols; rows>=65 of Km are zero)
    f32x4 accA[2][6];
#pragma unroll
    for (int i = 0; i < 2; ++i)
#pragma unroll
        for (int j = 0; j < 6; ++j) accA[i][j] = (f32x4)0.f;

#pragma unroll
    for (int kc = 0; kc < 2; ++kc) {
        f16x8 af[2], bf[6];
#pragma unroll
        for (int im = 0; im < 2; ++im) {
            int r = n0 + w * 32 + im * 16 + ln;
            if (r > 1024) r = 1024;
            af[im] = *(const f16x8*)(Qb + (size_t)r * 64 + (kc * 4 + q) * 8);
        }
#pragma unroll
        for (int in = 0; in < 6; ++in)
            bf[in] = *(const f16x8*)(Kmb + (size_t)(in * 16 + ln) * 64 + (kc * 4 + q) * 8);
#pragma unroll
        for (int im = 0; im < 2; ++im)
#pragma unroll
            for (int in = 0; in < 6; ++in)
                accA[im][in] = __builtin_amdgcn_mfma_f32_16x16x32_f16(
                    af[im], bf[in], accA[im][in], 0, 0, 0);
    }
#pragma unroll
    for (int im = 0; im < 2; ++im) {
        const int row = w * 32 + im * 16 + q * 4;
#pragma unroll
        for (int in = 0; in < 6; ++in) {
            const int col = in * 16 + ln;
#pragma unroll
            for (int reg = 0; reg < 4; ++reg)
                Ps[(row + reg) * 104 + col] = (_Float16)__expf(accA[im][in][reg]);
        }
    }
    __syncthreads();

    // phase B: prod = P(128x96) @ T2T^T(96x80); cols 0..63 ctx, col 64 = den
    f32x4 accB[2][5];
#pragma unroll
    for (int i = 0; i < 2; ++i)
#pragma unroll
        for (int j = 0; j < 5; ++j) accB[i][j] = (f32x4)0.f;
#pragma unroll
    for (int kc = 0; kc < 3; ++kc) {
        f16x8 pa[2], tb[5];
#pragma unroll
        for (int im = 0; im < 2; ++im)
            pa[im] = *(const f16x8*)&Ps[(w * 32 + im * 16 + ln) * 104 + (kc * 4 + q) * 8];
#pragma unroll
        for (int in = 0; in < 5; ++in)
            tb[in] = *(const f16x8*)(Tb + (size_t)(in * 16 + ln) * 96 + (kc * 4 + q) * 8);
#pragma unroll
        for (int im = 0; im < 2; ++im)
#pragma unroll
            for (int in = 0; in < 5; ++in)
                accB[im][in] = __builtin_amdgcn_mfma_f32_16x16x32_f16(
                    pa[im], tb[in], accB[im][in], 0, 0, 0);
    }
    if (ln == 0) {
#pragma unroll
        for (int im = 0; im < 2; ++im) {
            const int row = w * 32 + im * 16 + q * 4;
#pragma unroll
            for (int reg = 0; reg < 4; ++reg)
                dn[row + reg] = accB[im][4][reg];
        }
    }
    __syncthreads();
#pragma unroll
    for (int im = 0; im < 2; ++im) {
        const int rowb = w * 32 + im * 16 + q * 4;
#pragma unroll
        for (int reg = 0; reg < 4; ++reg) {
            const int n = n0 + rowb + reg;
            if (n < kN) {
                const float dv = fmaxf(dn[rowb + reg], 1e-8f);
                __half* dst = CTXh + ((size_t)bq * 1025 + n) * 768 + h * 64;
#pragma unroll
                for (int in = 0; in < 4; ++in)
                    dst[in * 16 + ln] = __float2half_rn(accB[im][in][reg] / dv);
            }
        }
    }
}

// ---------------------------------------------------------------------------
extern "C" void kernel_launch(void* const* d_in, const int* in_sizes, int n_in,
                              void* d_out, int out_size, void* d_ws, size_t ws_size,
                              hipStream_t stream)
{
    const float* x      = (const float*)d_in[0];
    const float* qkv_w  = (const float*)d_in[1];
    const float* qkv_b  = (const float*)d_in[2];
    const float* proj_w = (const float*)d_in[3];
    const float* proj_b = (const float*)d_in[4];
    float* out = (float*)d_out;

    __half* Xh = (__half*)d_out;
    __half* Qh = Xh + QSZ;
    float*  T1part = (float*)d_out;
    float*  Mpart  = T1part + (size_t)kBH * NSPLIT * 4225;
    __half* KMh  = (__half*)((char*)d_out + (size_t)27 * 1024 * 1024);
    __half* T2TH = (__half*)((char*)d_out + (size_t)33 * 1024 * 1024);

    __half* Kh   = (__half*)d_ws;
    __half* Vh   = Kh + QSZ;
    __half* CTXh = Kh;
    float*  QM   = (float*)(Vh + QSZ);
    float*  KM   = QM + QMSZ;
    float*  MAXC = KM + QMSZ;
    float*  EXPB = MAXC + (size_t)kBH * 65;
    float*  T1   = EXPB + SBSZ;
    float*  T2   = T1 + SBSZ;
    float*  RC   = T2 + SBSZ;
    float*  GMX  = RC + (size_t)kBH * 2;
    size_t woff = (size_t)(GMX + 1 - (float*)d_ws);
    woff = (woff + 3) & ~(size_t)3;
    __half* WqkvT = (__half*)((float*)d_ws + woff);
    __half* WprojT = WqkvT + (size_t)2304 * 768;

    cvt_f32_f16  <<<dim3((int)(QSZ / 4 / 256)), 256, 0, stream>>>(x, Xh, (int)(QSZ / 4));
    cvt_transpose<<<dim3(72, 24), dim3(32, 8), 0, stream>>>(qkv_w, WqkvT, 768, 2304);
    cvt_transpose<<<dim3(24, 24), dim3(32, 8), 0, stream>>>(proj_w, WprojT, 768, 768);

    gemm_mfma<0><<<dim3(18, 257), 256, 0, stream>>>(Xh, WqkvT, qkv_b,
                                                    nullptr, Qh, Kh, Vh);
    pool_kernel<<<dim3(96, kBH, 2), 64, 0, stream>>>(Qh, Kh, QM, KM, KMh);
    sct1_kernel<<<dim3(NSPLIT, kBH), 256, 0, stream>>>(QM, Kh, Vh, T1part, Mpart);
    t1comb_kernel<<<dim3(kBH), 256, 0, stream>>>(T1part, Mpart, T1, MAXC);
    expb_kernel<<<dim3(kBH), 512, 0, stream>>>(QM, KM, MAXC, EXPB, RC);
    alpha_kernel<<<dim3(1), 256, 0, stream>>>(RC, GMX);
    pinv_kernel<<<dim3(kBH), 512, 0, stream>>>(EXPB, T1, GMX, T2TH);
    prod_mfma  <<<dim3(9, kBH), 256, 0, stream>>>(Qh, KMh, T2TH, CTXh);
    gemm_mfma<1><<<dim3(6, 257), 256, 0, stream>>>(CTXh, WprojT, proj_b,
                                                   out, nullptr, nullptr, nullptr);
}

// Round 6
// 733.355 us; speedup vs baseline: 1.3265x; 1.1900x over previous
//
#include <hip/hip_runtime.h>
#include <hip/hip_fp16.h>

// ---------------------------------------------------------------------------
// TimmPnPNystromAttention  (B=32, N=1025, C=768, H=12, Dh=64, landmarks=64)
// Round 9: MFMA sct1 WITH exact maxC (R8 post-mortem: dropping maxC wrecks
// Newton-Schulz conditioning; truncated NS needs the row-equalized expB).
//  - maxc_mfma: S_C = Qm@K^T via fp16 MFMA (bitwise-same S as sct1), per-row
//    max via shfl_xor + cross-wave LDS; per-split partials MAXCp[bh][4][80].
//  - sct1_mfma: T1part = exp(S_C - maxC) @ v_aug via fp16 MFMA (maxC = max of
//    4 partials). No online rescale, no t1comb; pinv sums the 4 partials.
//  - expb: maxC restored (from MAXCp), conditioning identical to R7 baseline.
//
// d_out (100.8 MB): [ Xh fp16 (50.4) | Qh fp16 (50.4) ]  -> final fp32 out
//   Xh after gemm<0>: T1part(24.8MB) | @27M KMh | @33M T2TH | @39M QMh | @45M MAXCp
// ws (137.8 MB): Kh | Vh (fp16, CTXh aliases Kh) | fp32 smalls | WT fp16
// ---------------------------------------------------------------------------

constexpr int kN  = 1025;
constexpr int kNT = 32 * kN;      // 32800 tokens
constexpr int kBH = 32 * 12;      // 384
constexpr int NSPLIT = 4;         // n-dim split for sct1/maxc

constexpr size_t QSZ  = (size_t)kBH * kN * 64;   // 25190400 == out_size
constexpr size_t QMSZ = (size_t)kBH * 65 * 64;   // 1597440
constexpr size_t SBSZ = (size_t)kBH * 65 * 65;   // 1622400

typedef _Float16 f16x8 __attribute__((ext_vector_type(8)));
typedef float    f32x4 __attribute__((ext_vector_type(4)));

#define GLDS(gp, lp) __builtin_amdgcn_global_load_lds( \
    (const __attribute__((address_space(1))) void*)(gp), \
    (__attribute__((address_space(3))) void*)(lp), 16, 0, 0)

__device__ __forceinline__ float4 loadh4(const __half* p) {
    const __half2* q = (const __half2*)p;
    float2 a = __half22float2(q[0]);
    float2 b = __half22float2(q[1]);
    return make_float4(a.x, a.y, b.x, b.y);
}

// ---------------- K0a: fp32 -> fp16 elementwise (X) -------------------------
__global__ __launch_bounds__(256) void cvt_f32_f16(
    const float* __restrict__ src, __half* __restrict__ dst, int n4)
{
    int i = blockIdx.x * 256 + threadIdx.x;
    if (i < n4) {
        float4 v = ((const float4*)src)[i];
        __half2 h01 = __floats2half2_rn(v.x, v.y);
        __half2 h23 = __floats2half2_rn(v.z, v.w);
        ((__half2*)dst)[2 * i]     = h01;
        ((__half2*)dst)[2 * i + 1] = h23;
    }
}

// ---------------- K0b: W (rows x cols, fp32) -> WT (cols x rows, fp16) ------
__global__ __launch_bounds__(256) void cvt_transpose(
    const float* __restrict__ W, __half* __restrict__ WT, int rows, int cols)
{
    __shared__ float tile[32][33];
    const int n0 = blockIdx.x * 32, k0 = blockIdx.y * 32;
#pragma unroll
    for (int i = 0; i < 4; ++i)
        tile[threadIdx.y + i * 8][threadIdx.x] =
            W[(size_t)(k0 + threadIdx.y + i * 8) * cols + n0 + threadIdx.x];
    __syncthreads();
#pragma unroll
    for (int i = 0; i < 4; ++i)
        WT[(size_t)(n0 + threadIdx.y + i * 8) * rows + k0 + threadIdx.x] =
            __float2half_rn(tile[threadIdx.x][threadIdx.y + i * 8]);
}

// ---------------- K1/K9: fp16 MFMA GEMM, 128x128 tile, BK=64 ----------------
template<int MODE>
__global__ __launch_bounds__(256) void gemm_mfma(
    const __half* __restrict__ A, const __half* __restrict__ Bt,
    const float* __restrict__ bias,
    float* __restrict__ OutF, __half* __restrict__ Qo,
    __half* __restrict__ Ko, __half* __restrict__ Vo)
{
    __shared__ _Float16 SMEM[128 * 136];     // 34,816 B
    _Float16* As = SMEM;
    _Float16* Bs = SMEM + 128 * 64;
    const int t  = threadIdx.x;
    const int w  = t >> 6, L = t & 63;
    const int q  = L >> 4, ln = L & 15;
    const int wm = w >> 1, wn = w & 1;
    const int cb = blockIdx.x * 128, rb = blockIdx.y * 128;

    f32x4 acc[4][4];
#pragma unroll
    for (int i = 0; i < 4; ++i)
#pragma unroll
        for (int j = 0; j < 4; ++j) acc[i][j] = (f32x4)0.f;

    const int srow = L >> 3;
    const int sc   = L & 7;

    for (int kt = 0; kt < 12; ++kt) {
        const int k0 = kt * 64;
        __syncthreads();
#pragma unroll
        for (int i = 0; i < 4; ++i) {
            const int r0  = w * 32 + i * 8;
            const int row = r0 + srow;
            const int g   = sc ^ (row & 7);
            if (rb + row < kNT)
                GLDS(A + (size_t)(rb + row) * 768 + k0 + g * 8, &As[r0 * 64]);
            GLDS(Bt + (size_t)(cb + row) * 768 + k0 + g * 8, &Bs[r0 * 64]);
        }
        __syncthreads();
#pragma unroll
        for (int kc = 0; kc < 2; ++kc) {
            f16x8 af[4], bf[4];
#pragma unroll
            for (int im = 0; im < 4; ++im) {
                const int m    = wm * 64 + im * 16 + ln;
                const int slot = (kc * 4 + q) ^ (m & 7);
                af[im] = *(const f16x8*)&As[m * 64 + slot * 8];
            }
#pragma unroll
            for (int in = 0; in < 4; ++in) {
                const int n    = wn * 64 + in * 16 + ln;
                const int slot = (kc * 4 + q) ^ (n & 7);
                bf[in] = *(const f16x8*)&Bs[n * 64 + slot * 8];
            }
#pragma unroll
            for (int im = 0; im < 4; ++im)
#pragma unroll
                for (int in = 0; in < 4; ++in)
                    acc[im][in] = __builtin_amdgcn_mfma_f32_16x16x32_f16(
                        af[im], bf[in], acc[im][in], 0, 0, 0);
        }
    }

    float bcol[4];
#pragma unroll
    for (int in = 0; in < 4; ++in) bcol[in] = bias[cb + wn * 64 + in * 16 + ln];

    if (MODE == 0) {
        const int   which = cb / 768;
        const float scl   = (which == 0) ? 0.125f : 1.f;
        __syncthreads();
#pragma unroll
        for (int in = 0; in < 4; ++in) {
            const int col = wn * 64 + in * 16 + ln;
#pragma unroll
            for (int im = 0; im < 4; ++im) {
                const int rowb = wm * 64 + im * 16 + q * 4;
#pragma unroll
                for (int reg = 0; reg < 4; ++reg)
                    SMEM[(rowb + reg) * 136 + (col ^ (q << 4))] =
                        (_Float16)((acc[im][in][reg] + bcol[in]) * scl);
            }
        }
        __syncthreads();
        const int hb = (cb - which * 768) >> 6;
        __half* dstb = (which == 0) ? Qo : (which == 1) ? Ko : Vo;
#pragma unroll
        for (int s = 0; s < 8; ++s) {
            const int idx = t + s * 256;
            const int r = idx >> 4, ck = idx & 15;
            const int R = rb + r;
            if (R < kNT) {
                const int qr = (r >> 2) & 3;
                f16x8 v = *(const f16x8*)&SMEM[r * 136 + ((ck ^ (qr << 1)) << 3)];
                const int bidx = R / 1025, nn = R - bidx * 1025;
                const int h = hb + (ck >> 3), d0 = (ck & 7) * 8;
                *(f16x8*)(dstb + ((size_t)(bidx * 12 + h) * 1025 + nn) * 64 + d0) = v;
            }
        }
    } else {
#pragma unroll
        for (int im = 0; im < 4; ++im) {
            const int Rb2 = rb + wm * 64 + im * 16 + q * 4;
#pragma unroll
            for (int reg = 0; reg < 4; ++reg) {
                const int R = Rb2 + reg;
                if (R < kNT) {
#pragma unroll
                    for (int in = 0; in < 4; ++in) {
                        const int Ncol = cb + wn * 64 + in * 16 + ln;
                        OutF[(size_t)R * 768 + Ncol] = acc[im][in][reg] + bcol[in];
                    }
                }
            }
        }
    }
}

// ---------------- K2: landmark pooling (fp16 src -> fp32 + fp16 Qm/Km) -----
__global__ __launch_bounds__(64) void pool_kernel(
    const __half* __restrict__ Qh, const __half* __restrict__ Kh,
    float* __restrict__ QM, float* __restrict__ KM,
    __half* __restrict__ KMh, __half* __restrict__ QMh)
{
    const int d  = threadIdx.x;
    const int m  = blockIdx.x;
    const int bh = blockIdx.y;
    if (m >= 65) {
        if (blockIdx.z == 1)
            KMh[(size_t)bh * 6144 + m * 64 + d] = __float2half_rn(0.f);
        else if (m < 80)
            QMh[(size_t)bh * 5120 + m * 64 + d] = __float2half_rn(0.f);
        return;
    }
    const __half* sb = (blockIdx.z ? Kh : Qh) + (size_t)bh * kN * 64;
    float* dst = blockIdx.z ? KM : QM;
    float v;
    if (m == 0) {
        v = __half2float(sb[d]);
    } else {
        int l = m - 1, a = l >> 3, e = l & 7;
        const __half* base = sb + (size_t)(1 + a * 128 + e * 4) * 64 + d;
        float s = 0.f;
#pragma unroll
        for (int b4 = 0; b4 < 4; ++b4)
#pragma unroll
            for (int f = 0; f < 4; ++f)
                s += __half2float(base[(b4 * 32 + f) * 64]);
        v = s * 0.0625f;
    }
    dst[(size_t)bh * 65 * 64 + m * 64 + d] = v;
    if (blockIdx.z == 1)
        KMh[(size_t)bh * 6144 + m * 64 + d] = __float2half_rn(v);
    else
        QMh[(size_t)bh * 5120 + m * 64 + d] = __float2half_rn(v);
}

// ---------------- K3a: maxC partials via MFMA (bitwise-same S as sct1) ------
__global__ __launch_bounds__(256) void maxc_mfma(
    const __half* __restrict__ QMh, const __half* __restrict__ Kg,
    float* __restrict__ MAXCp)
{
    __shared__ _Float16 QmS[80 * 72];
    __shared__ float mxW[4][80];
    const int t = threadIdx.x;
    const int w = t >> 6, L = t & 63;
    const int q = L >> 4, ln = L & 15;
    const int sp = blockIdx.x, bh = blockIdx.y;
    const __half* Kb  = Kg  + (size_t)bh * 65600;
    const __half* Qmb = QMh + (size_t)bh * 5120;

    for (int s = 0; s < 3; ++s) {
        int idx = t + s * 256;
        if (idx < 640) {
            int r = idx >> 3, c8 = idx & 7;
            *(f16x8*)&QmS[r * 72 + c8 * 8] = *(const f16x8*)(Qmb + r * 64 + c8 * 8);
        }
    }
    const int ns = sp * 256;
    const int ne = (sp == 3) ? 1025 : ns + 256;
    f32x4 run[5];
#pragma unroll
    for (int im = 0; im < 5; ++im) run[im] = (f32x4)(-3e38f);
    __syncthreads();
    const int nch = (ne - ns + 63) >> 6;
    for (int c = 0; c < nch; ++c) {
        const int nc = ns + c * 64;
        const int n = nc + w * 16 + ln;
        const int n_eff = (n > 1024) ? 1024 : n;
        f32x4 accA[5];
#pragma unroll
        for (int im = 0; im < 5; ++im) accA[im] = (f32x4)0.f;
#pragma unroll
        for (int kc = 0; kc < 2; ++kc) {
            f16x8 bf = *(const f16x8*)(Kb + (size_t)n_eff * 64 + (kc * 4 + q) * 8);
#pragma unroll
            for (int im = 0; im < 5; ++im) {
                f16x8 af = *(const f16x8*)&QmS[(im * 16 + ln) * 72 + (kc * 4 + q) * 8];
                accA[im] = __builtin_amdgcn_mfma_f32_16x16x32_f16(af, bf, accA[im], 0, 0, 0);
            }
        }
        const bool valid = n < ne;
#pragma unroll
        for (int im = 0; im < 5; ++im)
#pragma unroll
            for (int reg = 0; reg < 4; ++reg)
                run[im][reg] = fmaxf(run[im][reg], valid ? accA[im][reg] : -3e38f);
    }
#pragma unroll
    for (int mk = 1; mk < 16; mk <<= 1)
#pragma unroll
        for (int im = 0; im < 5; ++im)
#pragma unroll
            for (int reg = 0; reg < 4; ++reg)
                run[im][reg] = fmaxf(run[im][reg], __shfl_xor(run[im][reg], mk));
    if (ln == 0) {
#pragma unroll
        for (int im = 0; im < 5; ++im)
#pragma unroll
            for (int reg = 0; reg < 4; ++reg)
                mxW[w][im * 16 + q * 4 + reg] = run[im][reg];
    }
    __syncthreads();
    if (t < 65)
        MAXCp[((size_t)bh * NSPLIT + sp) * 80 + t] =
            fmaxf(fmaxf(mxW[0][t], mxW[1][t]), fmaxf(mxW[2][t], mxW[3][t]));
}

// ---------------- K3b: MFMA T1part = exp(S_C - maxC) @ v_aug ----------------
__global__ __launch_bounds__(256) void sct1_mfma(
    const __half* __restrict__ QMh, const __half* __restrict__ Kg,
    const __half* __restrict__ Vg, const float* __restrict__ MAXCp,
    float* __restrict__ T1part)
{
    __shared__ _Float16 QmS[80 * 72];
    __shared__ _Float16 ExpS[80 * 72];
    __shared__ _Float16 VT[80 * 72];
    __shared__ float mcS[80];
    const int t = threadIdx.x;
    const int w = t >> 6, L = t & 63;
    const int q = L >> 4, ln = L & 15;
    const int sp = blockIdx.x, bh = blockIdx.y;
    const __half* Kb  = Kg  + (size_t)bh * 65600;
    const __half* Vb  = Vg  + (size_t)bh * 65600;
    const __half* Qmb = QMh + (size_t)bh * 5120;

    for (int s = 0; s < 3; ++s) {
        int idx = t + s * 256;
        if (idx < 640) {
            int r = idx >> 3, c8 = idx & 7;
            *(f16x8*)&QmS[r * 72 + c8 * 8] = *(const f16x8*)(Qmb + r * 64 + c8 * 8);
        }
    }
    if (t < 80) {
        float m = 0.f;
        if (t < 65) {
            const float* P = MAXCp + (size_t)bh * NSPLIT * 80;
            m = fmaxf(fmaxf(P[t], P[80 + t]), fmaxf(P[160 + t], P[240 + t]));
        }
        mcS[t] = m;
    }
    const int ns = sp * 256;
    const int ne = (sp == 3) ? 1025 : ns + 256;

    f32x4 acc2[2][5];
#pragma unroll
    for (int i = 0; i < 2; ++i)
#pragma unroll
        for (int j = 0; j < 5; ++j) acc2[i][j] = (f32x4)0.f;
    __syncthreads();

    const int nch = (ne - ns + 63) >> 6;
    for (int c = 0; c < nch; ++c) {
        const int nc = ns + c * 64;
        // stage V chunk transposed: VT[d][n_local], +ones row 64, pad 65..79=0
        {
            const int nl = t >> 2, d0 = (t & 3) * 16;
            const int n = nc + nl;
            const int n_eff = (n > 1024) ? 1024 : n;
            f16x8 v0 = *(const f16x8*)(Vb + (size_t)n_eff * 64 + d0);
            f16x8 v1 = *(const f16x8*)(Vb + (size_t)n_eff * 64 + d0 + 8);
#pragma unroll
            for (int j = 0; j < 8; ++j) VT[(d0 + j) * 72 + nl] = v0[j];
#pragma unroll
            for (int j = 0; j < 8; ++j) VT[(d0 + 8 + j) * 72 + nl] = v1[j];
        }
        if (t < 64) {
            VT[64 * 72 + t] = (_Float16)1.f;
#pragma unroll
            for (int r = 65; r < 80; ++r) VT[r * 72 + t] = (_Float16)0.f;
        }
        // phase A: S rows 0..79 for this wave's 16 cols
        f32x4 accA[5];
#pragma unroll
        for (int im = 0; im < 5; ++im) accA[im] = (f32x4)0.f;
        {
            const int n = nc + w * 16 + ln;
            const int n_eff = (n > 1024) ? 1024 : n;
#pragma unroll
            for (int kc = 0; kc < 2; ++kc) {
                f16x8 bf = *(const f16x8*)(Kb + (size_t)n_eff * 64 + (kc * 4 + q) * 8);
#pragma unroll
                for (int im = 0; im < 5; ++im) {
                    f16x8 af = *(const f16x8*)&QmS[(im * 16 + ln) * 72 + (kc * 4 + q) * 8];
                    accA[im] = __builtin_amdgcn_mfma_f32_16x16x32_f16(
                        af, bf, accA[im], 0, 0, 0);
                }
            }
        }
        {   // exp(S - maxC) -> ExpS (zero for n out of this split's range)
            const bool valid = (nc + w * 16 + ln) < ne;
            const int colL = w * 16 + ln;
#pragma unroll
            for (int im = 0; im < 5; ++im) {
                const int rowb = im * 16 + q * 4;
#pragma unroll
                for (int reg = 0; reg < 4; ++reg)
                    ExpS[(rowb + reg) * 72 + colL] =
                        valid ? (_Float16)__expf(accA[im][reg] - mcS[rowb + reg])
                              : (_Float16)0.f;
            }
        }
        __syncthreads();
        // phase B: wave's m-tile(s), k = 64 chunk cols
#pragma unroll
        for (int tt = 0; tt < 2; ++tt) {
            if (tt == 1 && w != 0) break;
            const int mt = (tt == 0) ? w : 4;
#pragma unroll
            for (int kc = 0; kc < 2; ++kc) {
                f16x8 pa = *(const f16x8*)&ExpS[(mt * 16 + ln) * 72 + (kc * 4 + q) * 8];
#pragma unroll
                for (int jn = 0; jn < 5; ++jn) {
                    f16x8 vb = *(const f16x8*)&VT[(jn * 16 + ln) * 72 + (kc * 4 + q) * 8];
                    acc2[tt][jn] = __builtin_amdgcn_mfma_f32_16x16x32_f16(
                        pa, vb, acc2[tt][jn], 0, 0, 0);
                }
            }
        }
        __syncthreads();
    }
    float* T1b = T1part + ((size_t)bh * NSPLIT + sp) * 4225;
#pragma unroll
    for (int tt = 0; tt < 2; ++tt) {
        if (tt == 1 && w != 0) continue;
        const int mt = (tt == 0) ? w : 4;
#pragma unroll
        for (int jn = 0; jn < 5; ++jn) {
            const int col = jn * 16 + ln;
            if (col >= 65) continue;
#pragma unroll
            for (int reg = 0; reg < 4; ++reg) {
                const int row = mt * 16 + q * 4 + reg;
                if (row < 65) T1b[row * 65 + col] = acc2[tt][jn][reg];
            }
        }
    }
}

// ---------------- K4: expB = exp(max(S_B - maxC, -88)); row/col sums --------
__global__ __launch_bounds__(512) void expb_kernel(
    const float* __restrict__ QM, const float* __restrict__ KM,
    const float* __restrict__ MAXCp, float* __restrict__ EXPB,
    float* __restrict__ RC)
{
    __shared__ float Qs[65][68];
    __shared__ float Ks[65][68];
    __shared__ float SB[65][68];
    __shared__ float mc[65];
    __shared__ float rs[65], cs[65];
    const int t = threadIdx.x, bh = blockIdx.x;
    const float* qm = QM + (size_t)bh * 4160;
    const float* km = KM + (size_t)bh * 4160;
    for (int s = 0; s < 3; ++s) {
        int idx = t + s * 512;
        if (idx < 1040) {
            int r = idx >> 4, c = (idx & 15) * 4;
            *(float4*)&Qs[r][c] = *(const float4*)(qm + r * 64 + c);
            *(float4*)&Ks[r][c] = *(const float4*)(km + r * 64 + c);
        }
    }
    if (t < 65) {
        const float* P = MAXCp + (size_t)bh * NSPLIT * 80;
        mc[t] = fmaxf(fmaxf(P[t], P[80 + t]), fmaxf(P[160 + t], P[240 + t]));
    }
    __syncthreads();

    const int tm = t >> 4, tj = t & 15;
    float acc[3][5];
#pragma unroll
    for (int i = 0; i < 3; ++i)
#pragma unroll
        for (int j = 0; j < 5; ++j) acc[i][j] = 0.f;
#pragma unroll 2
    for (int k4 = 0; k4 < 64; k4 += 4) {
        float Qa[3][4], Kb[5][4];
#pragma unroll
        for (int i = 0; i < 3; ++i) {
            float4 v4 = (i < 2) ? *(const float4*)&Qs[2 * tm + i][k4]
                                : *(const float4*)&Qs[64][k4];
            Qa[i][0] = v4.x; Qa[i][1] = v4.y; Qa[i][2] = v4.z; Qa[i][3] = v4.w;
        }
#pragma unroll
        for (int j = 0; j < 5; ++j) {
            float4 v4 = (j < 4) ? *(const float4*)&Ks[tj * 4 + j][k4]
                                : *(const float4*)&Ks[64][k4];
            Kb[j][0] = v4.x; Kb[j][1] = v4.y; Kb[j][2] = v4.z; Kb[j][3] = v4.w;
        }
#pragma unroll
        for (int kk = 0; kk < 4; ++kk)
#pragma unroll
            for (int i = 0; i < 3; ++i)
#pragma unroll
                for (int j = 0; j < 5; ++j)
                    acc[i][j] = fmaf(Qa[i][kk], Kb[j][kk], acc[i][j]);
    }
#pragma unroll
    for (int i = 0; i < 3; ++i) {
        if (i == 2 && tm != 0) continue;
        const int mi = (i < 2) ? 2 * tm + i : 64;
        const float mci = mc[mi];
#pragma unroll
        for (int j = 0; j < 5; ++j) {
            if (j == 4 && tj != 0) continue;
            const int jc = (j < 4) ? tj * 4 + j : 64;
            SB[mi][jc] = __expf(fmaxf(acc[i][j] - mci, -88.f));
        }
    }
    __syncthreads();
    for (int s = 0; s < 9; ++s) {
        int o = t + s * 512;
        if (o < 4225) EXPB[(size_t)bh * 4225 + o] = SB[o / 65][o % 65];
    }
    if (t < 65) {
        float r = 0.f, c = 0.f;
        for (int j = 0; j < 65; ++j) r += SB[t][j];
        for (int i = 0; i < 65; ++i) c += SB[i][t];
        rs[t] = r; cs[t] = c;
    }
    __syncthreads();
    if (t == 0) {
        float rm = 0.f, cm2 = 0.f;
        for (int i = 0; i < 65; ++i) { rm = fmaxf(rm, rs[i]); cm2 = fmaxf(cm2, cs[i]); }
        RC[bh * 2] = rm; RC[bh * 2 + 1] = cm2;
    }
}

// ---------------- K5: alpha = 1/(global_max_rowsum * global_max_colsum + eps)
__global__ __launch_bounds__(256) void alpha_kernel(
    const float* __restrict__ RC, float* __restrict__ GMX)
{
    __shared__ float sr[256], sc[256];
    const int t = threadIdx.x;
    float rm = 0.f, cm = 0.f;
    for (int i = t; i < kBH; i += 256) {
        rm = fmaxf(rm, RC[2 * i]);
        cm = fmaxf(cm, RC[2 * i + 1]);
    }
    sr[t] = rm; sc[t] = cm;
    __syncthreads();
    for (int s = 128; s > 0; s >>= 1) {
        if (t < s) { sr[t] = fmaxf(sr[t], sr[t + s]); sc[t] = fmaxf(sc[t], sc[t + s]); }
        __syncthreads();
    }
    if (t == 0) GMX[0] = 1.f / (sr[0] * sc[0] + 1e-15f);
}

// ---------------- K6: Newton-Schulz pinv (512 threads, 2x4 tile) ------------
__device__ __forceinline__ void mm65(const float (*Op1)[68], const float (*Op2)[68],
                                     float (*Dst)[68], const float (*Pre)[68],
                                     float c0, float c1, int tm, int tj)
{
    float acc[3][5];
#pragma unroll
    for (int i = 0; i < 3; ++i)
#pragma unroll
        for (int j = 0; j < 5; ++j) acc[i][j] = 0.f;
#pragma unroll 2
    for (int k4 = 0; k4 < 64; k4 += 4) {
        float Aa[3][4], Bb[4][4], c64[4];
#pragma unroll
        for (int i = 0; i < 3; ++i) {
            float4 v4 = (i < 2) ? *(const float4*)&Op1[2 * tm + i][k4]
                                : *(const float4*)&Op1[64][k4];
            Aa[i][0] = v4.x; Aa[i][1] = v4.y; Aa[i][2] = v4.z; Aa[i][3] = v4.w;
        }
#pragma unroll
        for (int kk = 0; kk < 4; ++kk) {
            float4 v4 = *(const float4*)&Op2[k4 + kk][tj * 4];
            Bb[kk][0] = v4.x; Bb[kk][1] = v4.y; Bb[kk][2] = v4.z; Bb[kk][3] = v4.w;
            c64[kk] = Op2[k4 + kk][64];
        }
#pragma unroll
        for (int kk = 0; kk < 4; ++kk)
#pragma unroll
            for (int i = 0; i < 3; ++i) {
                const float av = Aa[i][kk];
#pragma unroll
                for (int j = 0; j < 4; ++j)
                    acc[i][j] = fmaf(av, Bb[kk][j], acc[i][j]);
                acc[i][4] = fmaf(av, c64[kk], acc[i][4]);
            }
    }
    {   // tail k = 64
        float a3[3], b5[5];
        a3[0] = Op1[2 * tm][64]; a3[1] = Op1[2 * tm + 1][64]; a3[2] = Op1[64][64];
#pragma unroll
        for (int j = 0; j < 4; ++j) b5[j] = Op2[64][tj * 4 + j];
        b5[4] = Op2[64][64];
#pragma unroll
        for (int i = 0; i < 3; ++i)
#pragma unroll
            for (int j = 0; j < 5; ++j)
                acc[i][j] = fmaf(a3[i], b5[j], acc[i][j]);
    }
    float val[3][5];
#pragma unroll
    for (int i = 0; i < 3; ++i) {
        int mi = (i < 2) ? 2 * tm + i : 64;
#pragma unroll
        for (int j = 0; j < 5; ++j) {
            int jc = (j < 4) ? tj * 4 + j : 64;
            val[i][j] = c1 * (c0 * Pre[mi][jc] - acc[i][j]);
        }
    }
    __syncthreads();
#pragma unroll
    for (int i = 0; i < 3; ++i) {
        if (i == 2 && tm != 0) continue;
        int mi = (i < 2) ? 2 * tm + i : 64;
#pragma unroll
        for (int j = 0; j < 5; ++j) {
            if (j == 4 && tj != 0) continue;
            int jc = (j < 4) ? tj * 4 + j : 64;
            Dst[mi][jc] = val[i][j];
        }
    }
    __syncthreads();
}

__global__ __launch_bounds__(512) void pinv_kernel(
    const float* __restrict__ EXPB, const float* __restrict__ T1part,
    const float* __restrict__ GMX, __half* __restrict__ T2TH)
{
    __shared__ float Wb[65][68];
    __shared__ float Zb[65][68];
    __shared__ float Ab[65][68];
    const int t = threadIdx.x, bh = blockIdx.x;
    const int tm = t >> 4, tj = t & 15;
    const float alpha = GMX[0];
    const float* X = EXPB + (size_t)bh * 4225;
    for (int s = 0; s < 9; ++s) {
        int o = t + s * 512;
        if (o < 4225) Wb[o / 65][o % 65] = X[o];
    }
    __syncthreads();
    for (int s = 0; s < 9; ++s) {   // Z = alpha * X^T
        int o = t + s * 512;
        if (o < 4225) { int i = o / 65, j = o % 65; Zb[i][j] = alpha * Wb[j][i]; }
    }
    __syncthreads();
    for (int it = 0; it < 6; ++it) {
        if (it > 0) {
            for (int s = 0; s < 9; ++s) {
                int o = t + s * 512;
                if (o < 4225) Wb[o / 65][o % 65] = X[o];
            }
            __syncthreads();
        }
        mm65(Wb, Zb, Ab, Wb, 0.f,  -1.f,  tm, tj);  // A = X@Z
        mm65(Ab, Ab, Wb, Ab, 7.f,   1.f,  tm, tj);  // U = 7A - A@A    -> W
        mm65(Ab, Wb, Ab, Ab, 15.f,  1.f,  tm, tj);  // V = 15A - A@U   -> A
        mm65(Zb, Ab, Zb, Zb, 13.f,  0.25f, tm, tj); // Z = .25(13Z - Z@V)
    }
    {   // T1 = sum of 4 n-split partials
        const float* Tp = T1part + (size_t)bh * NSPLIT * 4225;
        for (int s = 0; s < 9; ++s) {
            int o = t + s * 512;
            if (o < 4225)
                Wb[o / 65][o % 65] = Tp[o] + Tp[4225 + o] + Tp[8450 + o] + Tp[12675 + o];
        }
    }
    __syncthreads();
    {
        float acc[3][5];
#pragma unroll
        for (int i = 0; i < 3; ++i)
#pragma unroll
            for (int j = 0; j < 5; ++j) acc[i][j] = 0.f;
#pragma unroll 2
        for (int k4 = 0; k4 < 64; k4 += 4) {
            float Aa[3][4], Bb[4][4], c64[4];
#pragma unroll
            for (int i = 0; i < 3; ++i) {
                float4 v4 = (i < 2) ? *(const float4*)&Zb[2 * tm + i][k4]
                                    : *(const float4*)&Zb[64][k4];
                Aa[i][0] = v4.x; Aa[i][1] = v4.y; Aa[i][2] = v4.z; Aa[i][3] = v4.w;
            }
#pragma unroll
            for (int kk = 0; kk < 4; ++kk) {
                float4 v4 = *(const float4*)&Wb[k4 + kk][tj * 4];
                Bb[kk][0] = v4.x; Bb[kk][1] = v4.y; Bb[kk][2] = v4.z; Bb[kk][3] = v4.w;
                c64[kk] = Wb[k4 + kk][64];
            }
#pragma unroll
            for (int kk = 0; kk < 4; ++kk)
#pragma unroll
                for (int i = 0; i < 3; ++i) {
                    const float av = Aa[i][kk];
#pragma unroll
                    for (int j = 0; j < 4; ++j)
                        acc[i][j] = fmaf(av, Bb[kk][j], acc[i][j]);
                    acc[i][4] = fmaf(av, c64[kk], acc[i][4]);
                }
        }
        {   // tail k = 64
            float a3[3], b5[5];
            a3[0] = Zb[2 * tm][64]; a3[1] = Zb[2 * tm + 1][64]; a3[2] = Zb[64][64];
#pragma unroll
            for (int j = 0; j < 4; ++j) b5[j] = Wb[64][tj * 4 + j];
            b5[4] = Wb[64][64];
#pragma unroll
            for (int i = 0; i < 3; ++i)
#pragma unroll
                for (int j = 0; j < 5; ++j)
                    acc[i][j] = fmaf(a3[i], b5[j], acc[i][j]);
        }
        __syncthreads();
#pragma unroll
        for (int i = 0; i < 3; ++i) {
            if (i == 2 && tm != 0) continue;
            int mi = (i < 2) ? 2 * tm + i : 64;
#pragma unroll
            for (int j = 0; j < 5; ++j) {
                if (j == 4 && tj != 0) continue;
                int jc = (j < 4) ? tj * 4 + j : 64;
                Ab[mi][jc] = acc[i][j];
            }
        }
    }
    __syncthreads();
    __half* dstT = T2TH + (size_t)bh * 7680;
    for (int o = t; o < 7680; o += 512) {
        int n = o / 96, k = o - n * 96;
        float v = (n < 65 && k < 65) ? Ab[k][n] : 0.f;
        dstT[o] = __float2half_rn(v);
    }
}

// ---------------- K8: MFMA prod: P=exp(Q@Km^T); ctx = (P@T2)/(P@t2den) ------
__global__ __launch_bounds__(256) void prod_mfma(
    const __half* __restrict__ Qg, const __half* __restrict__ KMh,
    const __half* __restrict__ T2TH, __half* __restrict__ CTXh)
{
    __shared__ _Float16 Ps[128 * 104];
    __shared__ float dn[128];
    const int t = threadIdx.x;
    const int w = t >> 6, L = t & 63;
    const int q = L >> 4, ln = L & 15;
    const int nb = blockIdx.x, bh = blockIdx.y;
    const int bq = bh / 12, h = bh % 12;
    const int n0 = nb * 128;
    const __half* Qb  = Qg   + (size_t)bh * 65600;
    const __half* Kmb = KMh  + (size_t)bh * 6144;
    const __half* Tb  = T2TH + (size_t)bh * 7680;

    f32x4 accA[2][6];
#pragma unroll
    for (int i = 0; i < 2; ++i)
#pragma unroll
        for (int j = 0; j < 6; ++j) accA[i][j] = (f32x4)0.f;

#pragma unroll
    for (int kc = 0; kc < 2; ++kc) {
        f16x8 af[2], bf[6];
#pragma unroll
        for (int im = 0; im < 2; ++im) {
            int r = n0 + w * 32 + im * 16 + ln;
            if (r > 1024) r = 1024;
            af[im] = *(const f16x8*)(Qb + (size_t)r * 64 + (kc * 4 + q) * 8);
        }
#pragma unroll
        for (int in = 0; in < 6; ++in)
            bf[in] = *(const f16x8*)(Kmb + (size_t)(in * 16 + ln) * 64 + (kc * 4 + q) * 8);
#pragma unroll
        for (int im = 0; im < 2; ++im)
#pragma unroll
            for (int in = 0; in < 6; ++in)
                accA[im][in] = __builtin_amdgcn_mfma_f32_16x16x32_f16(
                    af[im], bf[in], accA[im][in], 0, 0, 0);
    }
#pragma unroll
    for (int im = 0; im < 2; ++im) {
        const int row = w * 32 + im * 16 + q * 4;
#pragma unroll
        for (int in = 0; in < 6; ++in) {
            const int col = in * 16 + ln;
#pragma unroll
            for (int reg = 0; reg < 4; ++reg)
                Ps[(row + reg) * 104 + col] = (_Float16)__expf(accA[im][in][reg]);
        }
    }
    __syncthreads();

    f32x4 accB[2][5];
#pragma unroll
    for (int i = 0; i < 2; ++i)
#pragma unroll
        for (int j = 0; j < 5; ++j) accB[i][j] = (f32x4)0.f;
#pragma unroll
    for (int kc = 0; kc < 3; ++kc) {
        f16x8 pa[2], tb[5];
#pragma unroll
        for (int im = 0; im < 2; ++im)
            pa[im] = *(const f16x8*)&Ps[(w * 32 + im * 16 + ln) * 104 + (kc * 4 + q) * 8];
#pragma unroll
        for (int in = 0; in < 5; ++in)
            tb[in] = *(const f16x8*)(Tb + (size_t)(in * 16 + ln) * 96 + (kc * 4 + q) * 8);
#pragma unroll
        for (int im = 0; im < 2; ++im)
#pragma unroll
            for (int in = 0; in < 5; ++in)
                accB[im][in] = __builtin_amdgcn_mfma_f32_16x16x32_f16(
                    pa[im], tb[in], accB[im][in], 0, 0, 0);
    }
    if (ln == 0) {
#pragma unroll
        for (int im = 0; im < 2; ++im) {
            const int row = w * 32 + im * 16 + q * 4;
#pragma unroll
            for (int reg = 0; reg < 4; ++reg)
                dn[row + reg] = accB[im][4][reg];
        }
    }
    __syncthreads();
#pragma unroll
    for (int im = 0; im < 2; ++im) {
        const int rowb = w * 32 + im * 16 + q * 4;
#pragma unroll
        for (int reg = 0; reg < 4; ++reg) {
            const int n = n0 + rowb + reg;
            if (n < kN) {
                const float dv = fmaxf(dn[rowb + reg], 1e-8f);
                __half* dst = CTXh + ((size_t)bq * 1025 + n) * 768 + h * 64;
#pragma unroll
                for (int in = 0; in < 4; ++in)
                    dst[in * 16 + ln] = __float2half_rn(accB[im][in][reg] / dv);
            }
        }
    }
}

// ---------------------------------------------------------------------------
extern "C" void kernel_launch(void* const* d_in, const int* in_sizes, int n_in,
                              void* d_out, int out_size, void* d_ws, size_t ws_size,
                              hipStream_t stream)
{
    const float* x      = (const float*)d_in[0];
    const float* qkv_w  = (const float*)d_in[1];
    const float* qkv_b  = (const float*)d_in[2];
    const float* proj_w = (const float*)d_in[3];
    const float* proj_b = (const float*)d_in[4];
    float* out = (float*)d_out;

    __half* Xh = (__half*)d_out;
    __half* Qh = Xh + QSZ;
    float*  T1part = (float*)d_out;                        // 24.8 MiB
    __half* KMh   = (__half*)((char*)d_out + (size_t)27 * 1024 * 1024);
    __half* T2TH  = (__half*)((char*)d_out + (size_t)33 * 1024 * 1024);
    __half* QMh   = (__half*)((char*)d_out + (size_t)39 * 1024 * 1024);
    float*  MAXCp = (float*)((char*)d_out + (size_t)45 * 1024 * 1024);  // 480 KB

    __half* Kh   = (__half*)d_ws;
    __half* Vh   = Kh + QSZ;
    __half* CTXh = Kh;
    float*  QM   = (float*)(Vh + QSZ);
    float*  KM   = QM + QMSZ;
    float*  MAXC = KM + QMSZ;                 // slot retained (unused)
    float*  EXPB = MAXC + (size_t)kBH * 65;
    float*  T1   = EXPB + SBSZ;               // slot retained (unused)
    float*  T2   = T1 + SBSZ;                 // slot retained (unused)
    float*  RC   = T2 + SBSZ;
    float*  GMX  = RC + (size_t)kBH * 2;
    size_t woff = (size_t)(GMX + 1 - (float*)d_ws);
    woff = (woff + 3) & ~(size_t)3;
    __half* WqkvT = (__half*)((float*)d_ws + woff);
    __half* WprojT = WqkvT + (size_t)2304 * 768;

    cvt_f32_f16  <<<dim3((int)(QSZ / 4 / 256)), 256, 0, stream>>>(x, Xh, (int)(QSZ / 4));
    cvt_transpose<<<dim3(72, 24), dim3(32, 8), 0, stream>>>(qkv_w, WqkvT, 768, 2304);
    cvt_transpose<<<dim3(24, 24), dim3(32, 8), 0, stream>>>(proj_w, WprojT, 768, 768);

    gemm_mfma<0><<<dim3(18, 257), 256, 0, stream>>>(Xh, WqkvT, qkv_b,
                                                    nullptr, Qh, Kh, Vh);
    pool_kernel<<<dim3(96, kBH, 2), 64, 0, stream>>>(Qh, Kh, QM, KM, KMh, QMh);
    maxc_mfma  <<<dim3(NSPLIT, kBH), 256, 0, stream>>>(QMh, Kh, MAXCp);
    sct1_mfma  <<<dim3(NSPLIT, kBH), 256, 0, stream>>>(QMh, Kh, Vh, MAXCp, T1part);
    expb_kernel<<<dim3(kBH), 512, 0, stream>>>(QM, KM, MAXCp, EXPB, RC);
    alpha_kernel<<<dim3(1), 256, 0, stream>>>(RC, GMX);
    pinv_kernel<<<dim3(kBH), 512, 0, stream>>>(EXPB, T1part, GMX, T2TH);
    prod_mfma  <<<dim3(9, kBH), 256, 0, stream>>>(Qh, KMh, T2TH, CTXh);
    gemm_mfma<1><<<dim3(6, 257), 256, 0, stream>>>(CTXh, WprojT, proj_b,
                                                   out, nullptr, nullptr, nullptr);
}